// Round 4
// baseline (1656.142 us; speedup 1.0000x reference)
//
#include <hip/hip_runtime.h>

#define H 64
#define BKN 64            // destination nodes per bucket
#define NB_CAP 1600       // LDS histogram capacity (N <= 102400)

// ---------------------------------------------------------------------------
// Bucket histogram over dst>>6, LDS-privatized. 256 blocks grid-stride.
// ---------------------------------------------------------------------------
__global__ __launch_bounds__(256)
void bhist_kernel(const int* __restrict__ ei, int* __restrict__ bcount, int E, int N, int NB) {
    __shared__ int h[NB_CAP];
    int tid = threadIdx.x;
    for (int i = tid; i < NB; i += 256) h[i] = 0;
    __syncthreads();
    int stride = gridDim.x * 256;
    for (int e = blockIdx.x * 256 + tid; e < E; e += stride) {
        int s = ei[e];
        int d = ei[E + e];
        if ((unsigned)s < (unsigned)N && (unsigned)d < (unsigned)N)
            atomicAdd(&h[d >> 6], 1);
    }
    __syncthreads();
    for (int i = tid; i < NB; i += 256)
        if (h[i]) atomicAdd(&bcount[i], h[i]);
}

// ---------------------------------------------------------------------------
// Exclusive scan of bucket counts (single block). Writes bbase[0..NB] and
// seeds the padded cursor array (stride 16 ints = one 64B line per bucket).
// ---------------------------------------------------------------------------
__global__ __launch_bounds__(256)
void bscan_kernel(const int* __restrict__ bcount, int* __restrict__ bbase,
                  int* __restrict__ cursor, int NB) {
    __shared__ int sd[256];
    __shared__ int carry;
    int t = threadIdx.x;
    if (t == 0) carry = 0;
    __syncthreads();
    for (int start = 0; start < NB; start += 256) {
        int i = start + t;
        int v = (i < NB) ? bcount[i] : 0;
        sd[t] = v; __syncthreads();
        for (int off = 1; off < 256; off <<= 1) {
            int add = (t >= off) ? sd[t - off] : 0;
            __syncthreads();
            sd[t] += add;
            __syncthreads();
        }
        int excl = sd[t] - v + carry;
        if (i < NB) { bbase[i] = excl; cursor[i * 16] = excl; }
        __syncthreads();
        if (t == 0) carry += sd[255];
        __syncthreads();
    }
    if (t == 0) bbase[NB] = carry;
}

// ---------------------------------------------------------------------------
// Partition edges into dst-buckets. pairs[pos] = src | (dst&63)<<20.
// Cursor padded to 64B lines -> no same-line atomic serialization; writes per
// bucket are sequential -> line write-combining.
// ---------------------------------------------------------------------------
__global__ __launch_bounds__(256)
void part_kernel(const int* __restrict__ ei, int* __restrict__ cursor,
                 int* __restrict__ pairs, int E, int N) {
    int e = blockIdx.x * 256 + threadIdx.x;
    if (e >= E) return;
    int s = ei[e];
    int d = ei[E + e];
    if ((unsigned)s >= (unsigned)N || (unsigned)d >= (unsigned)N) return;
    int pos = atomicAdd(&cursor[(d >> 6) * 16], 1);
    pairs[pos] = s | ((d & 63) << 20);
}

// ---------------------------------------------------------------------------
// Layer-1 aggregate, one workgroup (4 waves) per bucket. LDS accumulator
// 64 rows x 64 feats; ds_add_f32, 2-way bank aliasing (free). Epilogue adds
// self term and stores coalesced.  bufA = x + segment_sum(x[src]).
// ---------------------------------------------------------------------------
__global__ __launch_bounds__(256)
void gagg1_kernel(const float* __restrict__ x, const int* __restrict__ bbase,
                  const int* __restrict__ pairs, float* __restrict__ bufA, int N) {
    __shared__ float acc[BKN * H];
    int b = blockIdx.x;
    int tid = threadIdx.x, wv = tid >> 6, lane = tid & 63;
    for (int i = tid; i < BKN * H; i += 256) acc[i] = 0.f;
    __syncthreads();
    int pb = bbase[b], pe = bbase[b + 1];
    for (int c = pb + wv * 64; c < pe; c += 256) {
        int cnt = min(64, pe - c);
        int mypair = (lane < cnt) ? pairs[c + lane] : 0;
        int j = 0;
        for (; j + 4 <= cnt; j += 4) {
            int p0 = __shfl(mypair, j);
            int p1 = __shfl(mypair, j + 1);
            int p2 = __shfl(mypair, j + 2);
            int p3 = __shfl(mypair, j + 3);
            float v0 = x[((p0 & 0xFFFFF) << 6) + lane];
            float v1 = x[((p1 & 0xFFFFF) << 6) + lane];
            float v2 = x[((p2 & 0xFFFFF) << 6) + lane];
            float v3 = x[((p3 & 0xFFFFF) << 6) + lane];
            atomicAdd(&acc[((p0 >> 20) << 6) + lane], v0);
            atomicAdd(&acc[((p1 >> 20) << 6) + lane], v1);
            atomicAdd(&acc[((p2 >> 20) << 6) + lane], v2);
            atomicAdd(&acc[((p3 >> 20) << 6) + lane], v3);
        }
        for (; j < cnt; ++j) {
            int p = __shfl(mypair, j);
            float v = x[((p & 0xFFFFF) << 6) + lane];
            atomicAdd(&acc[((p >> 20) << 6) + lane], v);
        }
    }
    __syncthreads();
    int node0 = b * BKN;
    for (int r = wv; r < BKN && node0 + r < N; r += 4) {
        int g = node0 + r;
        bufA[(g << 6) + lane] = acc[(r << 6) + lane] + x[(g << 6) + lane];
    }
}

// ---------------------------------------------------------------------------
// Layer-2 aggregate with folded BN: bufB = scale*segsum(h1) + deg*shift.
// Counts deg in LDS (lane 0 per edge).
// ---------------------------------------------------------------------------
__global__ __launch_bounds__(256)
void gagg2_kernel(const float* __restrict__ h1p, const float* __restrict__ scale,
                  const float* __restrict__ shiftv, const int* __restrict__ bbase,
                  const int* __restrict__ pairs, float* __restrict__ bufB, int N) {
    __shared__ float acc[BKN * H];
    __shared__ int degs[BKN];
    int b = blockIdx.x;
    int tid = threadIdx.x, wv = tid >> 6, lane = tid & 63;
    for (int i = tid; i < BKN * H; i += 256) acc[i] = 0.f;
    if (tid < BKN) degs[tid] = 0;
    __syncthreads();
    int pb = bbase[b], pe = bbase[b + 1];
    for (int c = pb + wv * 64; c < pe; c += 256) {
        int cnt = min(64, pe - c);
        int mypair = (lane < cnt) ? pairs[c + lane] : 0;
        int j = 0;
        for (; j + 4 <= cnt; j += 4) {
            int p0 = __shfl(mypair, j);
            int p1 = __shfl(mypair, j + 1);
            int p2 = __shfl(mypair, j + 2);
            int p3 = __shfl(mypair, j + 3);
            float v0 = h1p[((p0 & 0xFFFFF) << 6) + lane];
            float v1 = h1p[((p1 & 0xFFFFF) << 6) + lane];
            float v2 = h1p[((p2 & 0xFFFFF) << 6) + lane];
            float v3 = h1p[((p3 & 0xFFFFF) << 6) + lane];
            atomicAdd(&acc[((p0 >> 20) << 6) + lane], v0);
            atomicAdd(&acc[((p1 >> 20) << 6) + lane], v1);
            atomicAdd(&acc[((p2 >> 20) << 6) + lane], v2);
            atomicAdd(&acc[((p3 >> 20) << 6) + lane], v3);
            if (lane == 0) {
                atomicAdd(&degs[p0 >> 20], 1);
                atomicAdd(&degs[p1 >> 20], 1);
                atomicAdd(&degs[p2 >> 20], 1);
                atomicAdd(&degs[p3 >> 20], 1);
            }
        }
        for (; j < cnt; ++j) {
            int p = __shfl(mypair, j);
            float v = h1p[((p & 0xFFFFF) << 6) + lane];
            atomicAdd(&acc[((p >> 20) << 6) + lane], v);
            if (lane == 0) atomicAdd(&degs[p >> 20], 1);
        }
    }
    __syncthreads();
    int node0 = b * BKN;
    for (int r = wv; r < BKN && node0 + r < N; r += 4) {
        int g = node0 + r;
        bufB[(g << 6) + lane] = acc[(r << 6) + lane] * scale[lane]
                              + (float)degs[r] * shiftv[lane];
    }
}

// ---------------------------------------------------------------------------
// Thread-per-node 2-layer MLP (layer 1), in place on bufA.
// ---------------------------------------------------------------------------
__global__ __launch_bounds__(64)
void mlp1_kernel(float* hbuf,
                 const float* __restrict__ W1a, const float* __restrict__ B1a,
                 const float* __restrict__ W1b, const float* __restrict__ B1b,
                 int N) {
    int i = blockIdx.x * blockDim.x + threadIdx.x;
    if (i >= N) return;
    long long base = (long long)i * H;
    float h[H], u[H];
#pragma unroll
    for (int f = 0; f < H; ++f) h[f] = hbuf[base + f];
#pragma unroll
    for (int j = 0; j < H; ++j) u[j] = B1a[j];
#pragma unroll
    for (int k = 0; k < H; ++k) {
        float hk = h[k];
#pragma unroll
        for (int j = 0; j < H; ++j) u[j] = fmaf(hk, W1a[k * H + j], u[j]);
    }
#pragma unroll
    for (int j = 0; j < H; ++j) u[j] = fmaxf(u[j], 0.f);
#pragma unroll
    for (int j = 0; j < H; ++j) h[j] = B1b[j];
#pragma unroll
    for (int k = 0; k < H; ++k) {
        float uk = u[k];
#pragma unroll
        for (int j = 0; j < H; ++j) h[j] = fmaf(uk, W1b[k * H + j], h[j]);
    }
#pragma unroll
    for (int j = 0; j < H; ++j) hbuf[base + j] = h[j];
}

// Column sums + sumsq of h1p for batchnorm stats.
__global__ void colsum_kernel(const float* __restrict__ h1p, float* __restrict__ stats, int N) {
    int lane = threadIdx.x & 63;
    int wave = (int)((blockIdx.x * (long long)blockDim.x + threadIdx.x) >> 6);
    int nwaves = (int)(((long long)gridDim.x * blockDim.x) >> 6);
    float s = 0.f, s2 = 0.f;
    for (int r = wave; r < N; r += nwaves) {
        float v = h1p[(long long)r * H + lane];
        s += v;
        s2 += v * v;
    }
    unsafeAtomicAdd(&stats[lane], s);
    unsafeAtomicAdd(&stats[H + lane], s2);
}

__global__ void bn_finalize_kernel(const float* __restrict__ stats,
                                   const float* __restrict__ gamma,
                                   const float* __restrict__ beta,
                                   float* __restrict__ scale, float* __restrict__ shiftv, float n) {
    int f = threadIdx.x;
    if (f >= H) return;
    float mean = stats[f] / n;
    float var = stats[H + f] / n - mean * mean;   // biased, matches jnp.var
    var = fmaxf(var, 0.f);
    float s = gamma[f] * rsqrtf(var + 1e-5f);
    scale[f] = s;
    shiftv[f] = beta[f] - mean * s;
}

// Layer-2 MLP fused with final linear head (C=10); BN affine for self term.
__global__ __launch_bounds__(64)
void mlp2_kernel(const float* __restrict__ h1p, const float* __restrict__ scale,
                 const float* __restrict__ shiftv, const float* __restrict__ agg,
                 const float* __restrict__ W2a, const float* __restrict__ B2a,
                 const float* __restrict__ W2b, const float* __restrict__ B2b,
                 const float* __restrict__ LW, const float* __restrict__ LB,
                 float* __restrict__ out, int N) {
    int i = blockIdx.x * blockDim.x + threadIdx.x;
    if (i >= N) return;
    long long base = (long long)i * H;
    float h[H], u[H];
#pragma unroll
    for (int f = 0; f < H; ++f)
        h[f] = (h1p[base + f] * scale[f] + shiftv[f]) + agg[base + f];
#pragma unroll
    for (int j = 0; j < H; ++j) u[j] = B2a[j];
#pragma unroll
    for (int k = 0; k < H; ++k) {
        float hk = h[k];
#pragma unroll
        for (int j = 0; j < H; ++j) u[j] = fmaf(hk, W2a[k * H + j], u[j]);
    }
#pragma unroll
    for (int j = 0; j < H; ++j) u[j] = fmaxf(u[j], 0.f);
#pragma unroll
    for (int j = 0; j < H; ++j) h[j] = B2b[j];
#pragma unroll
    for (int k = 0; k < H; ++k) {
        float uk = u[k];
#pragma unroll
        for (int j = 0; j < H; ++j) h[j] = fmaf(uk, W2b[k * H + j], h[j]);
    }
#pragma unroll
    for (int c = 0; c < 10; ++c) {
        float acc = LB[c];
#pragma unroll
        for (int k = 0; k < H; ++k) acc = fmaf(h[k], LW[k * 10 + c], acc);
        out[(long long)i * 10 + c] = acc;
    }
}

extern "C" void kernel_launch(void* const* d_in, const int* in_sizes, int n_in,
                              void* d_out, int out_size, void* d_ws, size_t ws_size,
                              hipStream_t stream) {
    const float* x    = (const float*)d_in[0];
    const int*   ei   = (const int*)d_in[1];
    const float* w1a  = (const float*)d_in[2];
    const float* b1a  = (const float*)d_in[3];
    const float* w1b  = (const float*)d_in[4];
    const float* b1b  = (const float*)d_in[5];
    const float* bng  = (const float*)d_in[6];
    const float* bnb  = (const float*)d_in[7];
    const float* w2a  = (const float*)d_in[8];
    const float* b2a  = (const float*)d_in[9];
    const float* w2b  = (const float*)d_in[10];
    const float* b2b  = (const float*)d_in[11];
    const float* linw = (const float*)d_in[12];
    const float* linb = (const float*)d_in[13];

    int N = in_sizes[0] / H;       // 100000
    int E = in_sizes[1] / 2;       // 1600000
    int NB = (N + BKN - 1) / BKN;  // 1563 buckets (fits NB_CAP=1600)

    // ---- workspace layout ----
    float* ws     = (float*)d_ws;
    float* bufA   = ws;                          // N*H: agg1 -> h1p in place
    float* bufB   = ws + (size_t)N * H;          // N*H: layer-2 aggregate
    float* stats  = ws + 2 * (size_t)N * H;      // 128 (colsum+sumsq)
    float* scale  = stats + 128;                 // 64
    float* shiftv = stats + 192;                 // 64
    int*   bcount = (int*)(stats + 256);         // NB
    int*   bbase  = bcount + NB;                 // NB+1
    int*   cursor = bbase + (NB + 1);            // NB*16 (64B-padded)
    int*   pairs  = cursor + NB * 16;            // E

    hipMemsetAsync(stats, 0, 128 * sizeof(float), stream);
    hipMemsetAsync(bcount, 0, (size_t)NB * sizeof(int), stream);

    // bucketed edge partition (once; serves both layers)
    bhist_kernel<<<256, 256, 0, stream>>>(ei, bcount, E, N, NB);
    bscan_kernel<<<1, 256, 0, stream>>>(bcount, bbase, cursor, NB);
    part_kernel<<<(E + 255) / 256, 256, 0, stream>>>(ei, cursor, pairs, E, N);

    gagg1_kernel<<<NB, 256, 0, stream>>>(x, bbase, pairs, bufA, N);
    mlp1_kernel<<<(N + 63) / 64, 64, 0, stream>>>(bufA, w1a, b1a, w1b, b1b, N);
    colsum_kernel<<<512, 256, 0, stream>>>(bufA, stats, N);
    bn_finalize_kernel<<<1, 64, 0, stream>>>(stats, bng, bnb, scale, shiftv, (float)N);

    gagg2_kernel<<<NB, 256, 0, stream>>>(bufA, scale, shiftv, bbase, pairs, bufB, N);
    mlp2_kernel<<<(N + 63) / 64, 64, 0, stream>>>(bufA, scale, shiftv, bufB,
                                                  w2a, b2a, w2b, b2b, linw, linb,
                                                  (float*)d_out, N);
}

// Round 5
// 960.000 us; speedup vs baseline: 1.7251x; 1.7251x over previous
//
#include <hip/hip_runtime.h>

#define H 64
#define SCAN_CH 1024   // elements per scan block (256 threads x 4)

// ---------------------------------------------------------------------------
// CSR build (proven in R3): histogram, 3-phase scan, bucket fill
// ---------------------------------------------------------------------------
__global__ void hist_kernel(const int* __restrict__ ei, int* __restrict__ deg, int E, int N) {
    int e = blockIdx.x * blockDim.x + threadIdx.x;
    if (e >= E) return;
    int d = ei[E + e];
    if ((unsigned)d < (unsigned)N) atomicAdd(&deg[d], 1);
}

__global__ void scan1_kernel(const int* __restrict__ deg, int* __restrict__ psum, int N) {
    __shared__ int sd[256];
    int t = threadIdx.x;
    int base = blockIdx.x * SCAN_CH + t * 4;
    int s = 0;
#pragma unroll
    for (int k = 0; k < 4; ++k) { int idx = base + k; if (idx < N) s += deg[idx]; }
    sd[t] = s; __syncthreads();
    for (int off = 128; off > 0; off >>= 1) {
        if (t < off) sd[t] += sd[t + off];
        __syncthreads();
    }
    if (t == 0) psum[blockIdx.x] = sd[0];
}

__global__ void scan2_kernel(int* __restrict__ psum, int B) {
    __shared__ int sd[256];
    int t = threadIdx.x;
    int v = (t < B) ? psum[t] : 0;
    sd[t] = v; __syncthreads();
    for (int off = 1; off < 256; off <<= 1) {
        int add = (t >= off) ? sd[t - off] : 0;
        __syncthreads();
        sd[t] += add;
        __syncthreads();
    }
    if (t < B) psum[t] = sd[t] - v;   // exclusive
}

__global__ void scan3_kernel(const int* __restrict__ deg, const int* __restrict__ psum,
                             int* __restrict__ rowptr, int* __restrict__ cursor, int N, int E) {
    __shared__ int sd[256];
    int t = threadIdx.x;
    int base = blockIdx.x * SCAN_CH + t * 4;
    int v[4]; int s = 0;
#pragma unroll
    for (int k = 0; k < 4; ++k) { int idx = base + k; v[k] = (idx < N) ? deg[idx] : 0; s += v[k]; }
    sd[t] = s; __syncthreads();
    int mine = s;
    for (int off = 1; off < 256; off <<= 1) {
        int add = (t >= off) ? sd[t - off] : 0;
        __syncthreads();
        sd[t] += add;
        __syncthreads();
    }
    int run = sd[t] - mine + psum[blockIdx.x];
#pragma unroll
    for (int k = 0; k < 4; ++k) {
        int idx = base + k;
        if (idx < N) {
            rowptr[idx] = run; cursor[idx] = run;
            run += v[k];
            if (idx == N - 1) rowptr[N] = run;
        }
    }
}

__global__ void fill_kernel(const int* __restrict__ ei, int* __restrict__ cursor,
                            int* __restrict__ ebuf, int E, int N) {
    int e = blockIdx.x * blockDim.x + threadIdx.x;
    if (e >= E) return;
    int s = ei[e];
    int d = ei[E + e];
    if ((unsigned)s >= (unsigned)N || (unsigned)d >= (unsigned)N) return;
    int p = atomicAdd(&cursor[d], 1);
    ebuf[p] = s;
}

// ---------------------------------------------------------------------------
// Fold the linear head into layer-2's second GEMM:
//   (relu(z)@W2b + b2b)@LW + LB  ==  relu(z)@(W2b@LW) + (b2b@LW + LB)
// Wf: [64][10], bf: [10].
// ---------------------------------------------------------------------------
__global__ void fold_head_kernel(const float* __restrict__ W2b, const float* __restrict__ B2b,
                                 const float* __restrict__ LW, const float* __restrict__ LB,
                                 float* __restrict__ Wf, float* __restrict__ bf) {
    int t = blockIdx.x * blockDim.x + threadIdx.x;
    if (t < 640) {
        int k = t / 10, c = t % 10;
        float a = 0.f;
        for (int m = 0; m < H; ++m) a = fmaf(W2b[k * H + m], LW[m * 10 + c], a);
        Wf[t] = a;
    } else if (t < 650) {
        int c = t - 640;
        float a = LB[c];
        for (int m = 0; m < H; ++m) a = fmaf(B2b[m], LW[m * 10 + c], a);
        bf[c] = a;
    }
}

// ---------------------------------------------------------------------------
// Fused layer 1: wave-per-node grid-stride.
//   gather (8-wide ILP) -> LDS row -> wave-parallel MLP (weights in VGPRs,
//   lane j owns output column j) -> h1p store + BN stats in registers.
// One block-reduced stats atomic set per block.
// ---------------------------------------------------------------------------
__global__ __launch_bounds__(256)
void layer1_kernel(const float* __restrict__ x, const int* __restrict__ rowptr,
                   const int* __restrict__ ebuf,
                   const float* __restrict__ W1a, const float* __restrict__ B1a,
                   const float* __restrict__ W1b, const float* __restrict__ B1b,
                   float* __restrict__ h1p, float* __restrict__ stats,
                   int N, int nwaves) {
    __shared__ float hrow[4][H];
    __shared__ float urow[4][H];
    __shared__ float sred[4][H];
    __shared__ float s2red[4][H];
    int lane = threadIdx.x & 63;
    int wv = threadIdx.x >> 6;
    int wid = blockIdx.x * 4 + wv;

    float w1a_r[H], w1b_r[H];
#pragma unroll
    for (int k = 0; k < H; ++k) w1a_r[k] = W1a[k * H + lane];
#pragma unroll
    for (int k = 0; k < H; ++k) w1b_r[k] = W1b[k * H + lane];
    float b1a_r = B1a[lane], b1b_r = B1b[lane];

    float s = 0.f, s2 = 0.f;
    for (int node = wid; node < N; node += nwaves) {
        int p = rowptr[node], pe = rowptr[node + 1];
        float acc = x[(node << 6) + lane];
        for (; p < pe; p += 8) {
            float v0 = 0.f, v1 = 0.f, v2 = 0.f, v3 = 0.f;
            float v4 = 0.f, v5 = 0.f, v6 = 0.f, v7 = 0.f;
            if (p + 0 < pe) v0 = x[(ebuf[p + 0] << 6) + lane];
            if (p + 1 < pe) v1 = x[(ebuf[p + 1] << 6) + lane];
            if (p + 2 < pe) v2 = x[(ebuf[p + 2] << 6) + lane];
            if (p + 3 < pe) v3 = x[(ebuf[p + 3] << 6) + lane];
            if (p + 4 < pe) v4 = x[(ebuf[p + 4] << 6) + lane];
            if (p + 5 < pe) v5 = x[(ebuf[p + 5] << 6) + lane];
            if (p + 6 < pe) v6 = x[(ebuf[p + 6] << 6) + lane];
            if (p + 7 < pe) v7 = x[(ebuf[p + 7] << 6) + lane];
            acc += ((v0 + v1) + (v2 + v3)) + ((v4 + v5) + (v6 + v7));
        }
        hrow[wv][lane] = acc;
        float u = b1a_r;
#pragma unroll
        for (int k = 0; k < H; ++k) u = fmaf(hrow[wv][k], w1a_r[k], u);
        u = fmaxf(u, 0.f);
        urow[wv][lane] = u;
        float h1 = b1b_r;
#pragma unroll
        for (int k = 0; k < H; ++k) h1 = fmaf(urow[wv][k], w1b_r[k], h1);
        h1p[(node << 6) + lane] = h1;
        s += h1;
        s2 = fmaf(h1, h1, s2);
    }
    sred[wv][lane] = s;
    s2red[wv][lane] = s2;
    __syncthreads();
    if (wv == 0) {
        float ts  = (sred[0][lane] + sred[1][lane]) + (sred[2][lane] + sred[3][lane]);
        float ts2 = (s2red[0][lane] + s2red[1][lane]) + (s2red[2][lane] + s2red[3][lane]);
        unsafeAtomicAdd(&stats[lane], ts);
        unsafeAtomicAdd(&stats[H + lane], ts2);
    }
}

__global__ void bn_finalize_kernel(const float* __restrict__ stats,
                                   const float* __restrict__ gamma,
                                   const float* __restrict__ beta,
                                   float* __restrict__ scale, float* __restrict__ shiftv, float n) {
    int f = threadIdx.x;
    if (f >= H) return;
    float mean = stats[f] / n;
    float var = stats[H + f] / n - mean * mean;   // biased, matches jnp.var
    var = fmaxf(var, 0.f);
    float s = gamma[f] * rsqrtf(var + 1e-5f);
    scale[f] = s;
    shiftv[f] = beta[f] - mean * s;
}

// ---------------------------------------------------------------------------
// Fused layer 2: gather h1 (8-wide), fold BN affine:
//   h_in2 = scale*(self + sum) + (deg+1)*shift
// then MLP with W2a (VGPRs) and folded head Wf (VGPRs, lanes 0..9 valid).
// ---------------------------------------------------------------------------
__global__ __launch_bounds__(256)
void layer2_kernel(const float* __restrict__ h1p, const float* __restrict__ scale,
                   const float* __restrict__ shiftv, const int* __restrict__ rowptr,
                   const int* __restrict__ ebuf,
                   const float* __restrict__ W2a, const float* __restrict__ B2a,
                   const float* __restrict__ Wf, const float* __restrict__ bf,
                   float* __restrict__ out, int N, int nwaves) {
    __shared__ float hrow[4][H];
    __shared__ float urow[4][H];
    int lane = threadIdx.x & 63;
    int wv = threadIdx.x >> 6;
    int wid = blockIdx.x * 4 + wv;

    float w2a_r[H], wf_r[H];
    int cl = (lane < 10) ? lane : 9;
#pragma unroll
    for (int k = 0; k < H; ++k) w2a_r[k] = W2a[k * H + lane];
#pragma unroll
    for (int k = 0; k < H; ++k) wf_r[k] = Wf[k * 10 + cl];
    float b2a_r = B2a[lane];
    float bf_r = bf[cl];
    float sc = scale[lane], sh = shiftv[lane];

    for (int node = wid; node < N; node += nwaves) {
        int p = rowptr[node], pe = rowptr[node + 1];
        float deg = (float)(pe - p);
        float acc = h1p[(node << 6) + lane];
        for (; p < pe; p += 8) {
            float v0 = 0.f, v1 = 0.f, v2 = 0.f, v3 = 0.f;
            float v4 = 0.f, v5 = 0.f, v6 = 0.f, v7 = 0.f;
            if (p + 0 < pe) v0 = h1p[(ebuf[p + 0] << 6) + lane];
            if (p + 1 < pe) v1 = h1p[(ebuf[p + 1] << 6) + lane];
            if (p + 2 < pe) v2 = h1p[(ebuf[p + 2] << 6) + lane];
            if (p + 3 < pe) v3 = h1p[(ebuf[p + 3] << 6) + lane];
            if (p + 4 < pe) v4 = h1p[(ebuf[p + 4] << 6) + lane];
            if (p + 5 < pe) v5 = h1p[(ebuf[p + 5] << 6) + lane];
            if (p + 6 < pe) v6 = h1p[(ebuf[p + 6] << 6) + lane];
            if (p + 7 < pe) v7 = h1p[(ebuf[p + 7] << 6) + lane];
            acc += ((v0 + v1) + (v2 + v3)) + ((v4 + v5) + (v6 + v7));
        }
        // folded BN: scale*(self+sum) + (deg+1)*shift
        hrow[wv][lane] = fmaf(acc, sc, (deg + 1.f) * sh);
        float u = b2a_r;
#pragma unroll
        for (int k = 0; k < H; ++k) u = fmaf(hrow[wv][k], w2a_r[k], u);
        u = fmaxf(u, 0.f);
        urow[wv][lane] = u;
        float o = bf_r;
#pragma unroll
        for (int k = 0; k < H; ++k) o = fmaf(urow[wv][k], wf_r[k], o);
        if (lane < 10) out[node * 10 + lane] = o;
    }
}

extern "C" void kernel_launch(void* const* d_in, const int* in_sizes, int n_in,
                              void* d_out, int out_size, void* d_ws, size_t ws_size,
                              hipStream_t stream) {
    const float* x    = (const float*)d_in[0];
    const int*   ei   = (const int*)d_in[1];
    const float* w1a  = (const float*)d_in[2];
    const float* b1a  = (const float*)d_in[3];
    const float* w1b  = (const float*)d_in[4];
    const float* b1b  = (const float*)d_in[5];
    const float* bng  = (const float*)d_in[6];
    const float* bnb  = (const float*)d_in[7];
    const float* w2a  = (const float*)d_in[8];
    const float* b2a  = (const float*)d_in[9];
    const float* w2b  = (const float*)d_in[10];
    const float* b2b  = (const float*)d_in[11];
    const float* linw = (const float*)d_in[12];
    const float* linb = (const float*)d_in[13];

    int N = in_sizes[0] / H;       // 100000
    int E = in_sizes[1] / 2;       // 1600000

    // ---- workspace layout ----
    float* ws     = (float*)d_ws;
    float* h1p    = ws;                          // N*H
    float* stats  = ws + (size_t)N * H;          // 128
    float* scale  = stats + 128;                 // 64
    float* shiftv = stats + 192;                 // 64
    float* Wf     = stats + 256;                 // 640
    float* bf     = Wf + 640;                    // 16
    int*   deg    = (int*)(bf + 16);             // N
    int*   rowptr = deg + N;                     // N+1
    int*   cursor = rowptr + (N + 1);            // N
    int*   psum   = cursor + N;                  // <=256
    int*   ebuf   = psum + 256;                  // E

    int B = (N + SCAN_CH - 1) / SCAN_CH;

    hipMemsetAsync(deg, 0, (size_t)N * sizeof(int), stream);
    hipMemsetAsync(stats, 0, 128 * sizeof(float), stream);

    // CSR build (once; serves both layers)
    hist_kernel<<<(E + 255) / 256, 256, 0, stream>>>(ei, deg, E, N);
    scan1_kernel<<<B, 256, 0, stream>>>(deg, psum, N);
    scan2_kernel<<<1, 256, 0, stream>>>(psum, B);
    scan3_kernel<<<B, 256, 0, stream>>>(deg, psum, rowptr, cursor, N, E);
    fill_kernel<<<(E + 255) / 256, 256, 0, stream>>>(ei, cursor, ebuf, E, N);
    fold_head_kernel<<<3, 256, 0, stream>>>(w2b, b2b, linw, linb, Wf, bf);

    const int LBLK = 1024;                       // 4096 waves, grid-stride
    int nwaves = LBLK * 4;
    layer1_kernel<<<LBLK, 256, 0, stream>>>(x, rowptr, ebuf, w1a, b1a, w1b, b1b,
                                            h1p, stats, N, nwaves);
    bn_finalize_kernel<<<1, 64, 0, stream>>>(stats, bng, bnb, scale, shiftv, (float)N);
    layer2_kernel<<<LBLK, 256, 0, stream>>>(h1p, scale, shiftv, rowptr, ebuf,
                                            w2a, b2a, Wf, bf, (float*)d_out, N, nwaves);
}

// Round 6
// 602.891 us; speedup vs baseline: 2.7470x; 1.5923x over previous
//
#include <hip/hip_runtime.h>

#define H 64
#define BKN 64            // destination nodes per bucket
#define NB_CAP 1600       // LDS histogram capacity (N <= 102400)

// ---------------------------------------------------------------------------
// Bucket histogram over dst>>6, LDS-privatized (R4-proven).
// ---------------------------------------------------------------------------
__global__ __launch_bounds__(256)
void bhist_kernel(const int* __restrict__ ei, int* __restrict__ bcount, int E, int N, int NB) {
    __shared__ int h[NB_CAP];
    int tid = threadIdx.x;
    for (int i = tid; i < NB; i += 256) h[i] = 0;
    __syncthreads();
    int stride = gridDim.x * 256;
    for (int e = blockIdx.x * 256 + tid; e < E; e += stride) {
        int s = ei[e];
        int d = ei[E + e];
        if ((unsigned)s < (unsigned)N && (unsigned)d < (unsigned)N)
            atomicAdd(&h[d >> 6], 1);
    }
    __syncthreads();
    for (int i = tid; i < NB; i += 256)
        if (h[i]) atomicAdd(&bcount[i], h[i]);
}

// ---------------------------------------------------------------------------
// Exclusive scan of bucket counts (single block, chunked with carry).
// Seeds padded cursors; writes bbase[NB] and rowptr[N] = total.
// ---------------------------------------------------------------------------
__global__ __launch_bounds__(256)
void bscan_kernel(const int* __restrict__ bcount, int* __restrict__ bbase,
                  int* __restrict__ cursor, int* __restrict__ rowptr, int NB) {
    __shared__ int sd[256];
    __shared__ int carry;
    int t = threadIdx.x;
    if (t == 0) carry = 0;
    __syncthreads();
    for (int start = 0; start < NB; start += 256) {
        int i = start + t;
        int v = (i < NB) ? bcount[i] : 0;
        sd[t] = v; __syncthreads();
        for (int off = 1; off < 256; off <<= 1) {
            int add = (t >= off) ? sd[t - off] : 0;
            __syncthreads();
            sd[t] += add;
            __syncthreads();
        }
        int excl = sd[t] - v + carry;
        if (i < NB) { bbase[i] = excl; cursor[i * 16] = excl; }
        __syncthreads();
        if (t == 0) carry += sd[255];
        __syncthreads();
    }
    if (t == 0) { bbase[NB] = carry; rowptr[(size_t)NB * BKN < 0 ? 0 : 0] = 0; }
    // rowptr[N] written below by host-known N: use bbase[NB] via bucket_csr? No:
    // we write rowptr[N] here directly (N == NB*BKN rounded down handled by caller arg).
}

__global__ void rowptr_tail_kernel(const int* __restrict__ bbase, int* __restrict__ rowptr,
                                   int N, int NB) {
    if (threadIdx.x == 0 && blockIdx.x == 0) rowptr[N] = bbase[NB];
}

// ---------------------------------------------------------------------------
// Partition edges into dst-buckets. pairs[pos] = src | (dst&63)<<20.
// Cursors padded to 64B lines; writes sequential within each bucket region.
// ---------------------------------------------------------------------------
__global__ __launch_bounds__(256)
void part_kernel(const int* __restrict__ ei, int* __restrict__ cursor,
                 int* __restrict__ pairs, int E, int N) {
    int e = blockIdx.x * 256 + threadIdx.x;
    if (e >= E) return;
    int s = ei[e];
    int d = ei[E + e];
    if ((unsigned)s >= (unsigned)N || (unsigned)d >= (unsigned)N) return;
    int pos = atomicAdd(&cursor[(d >> 6) * 16], 1);
    pairs[pos] = s | ((d & 63) << 20);
}

// ---------------------------------------------------------------------------
// Per-bucket local CSR: 64-bin LDS histogram + single-wave prefix scan ->
// rowptr, then scatter src into the bucket's CONTIGUOUS ebuf segment.
// All global writes land in a ~4KB region per block -> coalesced.
// ---------------------------------------------------------------------------
__global__ __launch_bounds__(256)
void bucket_csr_kernel(const int* __restrict__ pairs, const int* __restrict__ bbase,
                       int* __restrict__ ebuf, int* __restrict__ rowptr, int N) {
    __shared__ int hist[BKN];
    __shared__ int cur[BKN];
    int b = blockIdx.x;
    int tid = threadIdx.x;
    if (tid < BKN) hist[tid] = 0;
    __syncthreads();
    int pb = bbase[b], pe = bbase[b + 1];
    for (int i = pb + tid; i < pe; i += 256)
        atomicAdd(&hist[(pairs[i] >> 20) & 63], 1);
    __syncthreads();
    if (tid < BKN) {                      // first wave: shfl prefix scan of 64 bins
        int v = hist[tid];
        int incl = v;
        for (int off = 1; off < 64; off <<= 1) {
            int o = __shfl_up(incl, off);
            if (tid >= off) incl += o;
        }
        int excl = incl - v;
        cur[tid] = excl;
        int node = b * BKN + tid;
        if (node < N) rowptr[node] = pb + excl;
    }
    __syncthreads();
    for (int i = pb + tid; i < pe; i += 256) {
        int p = pairs[i];
        int pos = atomicAdd(&cur[(p >> 20) & 63], 1);
        ebuf[pb + pos] = p & 0xFFFFF;
    }
}

// ---------------------------------------------------------------------------
// Fold linear head into layer-2's second GEMM:
//   (relu(z)@W2b + b2b)@LW + LB == relu(z)@(W2b@LW) + (b2b@LW + LB)
// ---------------------------------------------------------------------------
__global__ void fold_head_kernel(const float* __restrict__ W2b, const float* __restrict__ B2b,
                                 const float* __restrict__ LW, const float* __restrict__ LB,
                                 float* __restrict__ Wf, float* __restrict__ bf) {
    int t = blockIdx.x * blockDim.x + threadIdx.x;
    if (t < 640) {
        int k = t / 10, c = t % 10;
        float a = 0.f;
        for (int m = 0; m < H; ++m) a = fmaf(W2b[k * H + m], LW[m * 10 + c], a);
        Wf[t] = a;
    } else if (t < 650) {
        int c = t - 640;
        float a = LB[c];
        for (int m = 0; m < H; ++m) a = fmaf(B2b[m], LW[m * 10 + c], a);
        bf[c] = a;
    }
}

// ---------------------------------------------------------------------------
// Layer-1 gather (R3-proven shape, 8-wide ILP): wave per node, lane = feature.
// bufA = x[i] + sum_{j->i} x[j]
// ---------------------------------------------------------------------------
__global__ __launch_bounds__(256)
void gather1_kernel(const float* __restrict__ x, const int* __restrict__ rowptr,
                    const int* __restrict__ ebuf, float* __restrict__ bufA, int N) {
    int wid = (int)(((long long)blockIdx.x * blockDim.x + threadIdx.x) >> 6);
    int lane = threadIdx.x & 63;
    if (wid >= N) return;
    int p = rowptr[wid], pe = rowptr[wid + 1];
    float acc = x[((long long)wid << 6) + lane];
    for (; p < pe; p += 8) {
        float v0 = 0.f, v1 = 0.f, v2 = 0.f, v3 = 0.f;
        float v4 = 0.f, v5 = 0.f, v6 = 0.f, v7 = 0.f;
        if (p + 0 < pe) v0 = x[((long long)ebuf[p + 0] << 6) + lane];
        if (p + 1 < pe) v1 = x[((long long)ebuf[p + 1] << 6) + lane];
        if (p + 2 < pe) v2 = x[((long long)ebuf[p + 2] << 6) + lane];
        if (p + 3 < pe) v3 = x[((long long)ebuf[p + 3] << 6) + lane];
        if (p + 4 < pe) v4 = x[((long long)ebuf[p + 4] << 6) + lane];
        if (p + 5 < pe) v5 = x[((long long)ebuf[p + 5] << 6) + lane];
        if (p + 6 < pe) v6 = x[((long long)ebuf[p + 6] << 6) + lane];
        if (p + 7 < pe) v7 = x[((long long)ebuf[p + 7] << 6) + lane];
        acc += ((v0 + v1) + (v2 + v3)) + ((v4 + v5) + (v6 + v7));
    }
    bufA[((long long)wid << 6) + lane] = acc;
}

// ---------------------------------------------------------------------------
// Layer-2 gather with folded BN: bufB = scale*segsum(h1) + deg*shift
// ---------------------------------------------------------------------------
__global__ __launch_bounds__(256)
void gather2_kernel(const float* __restrict__ h1p, const float* __restrict__ scale,
                    const float* __restrict__ shiftv, const int* __restrict__ rowptr,
                    const int* __restrict__ ebuf, float* __restrict__ bufB, int N) {
    int wid = (int)(((long long)blockIdx.x * blockDim.x + threadIdx.x) >> 6);
    int lane = threadIdx.x & 63;
    if (wid >= N) return;
    int p0 = rowptr[wid], pe = rowptr[wid + 1];
    int p = p0;
    float acc = 0.f;
    for (; p < pe; p += 8) {
        float v0 = 0.f, v1 = 0.f, v2 = 0.f, v3 = 0.f;
        float v4 = 0.f, v5 = 0.f, v6 = 0.f, v7 = 0.f;
        if (p + 0 < pe) v0 = h1p[((long long)ebuf[p + 0] << 6) + lane];
        if (p + 1 < pe) v1 = h1p[((long long)ebuf[p + 1] << 6) + lane];
        if (p + 2 < pe) v2 = h1p[((long long)ebuf[p + 2] << 6) + lane];
        if (p + 3 < pe) v3 = h1p[((long long)ebuf[p + 3] << 6) + lane];
        if (p + 4 < pe) v4 = h1p[((long long)ebuf[p + 4] << 6) + lane];
        if (p + 5 < pe) v5 = h1p[((long long)ebuf[p + 5] << 6) + lane];
        if (p + 6 < pe) v6 = h1p[((long long)ebuf[p + 6] << 6) + lane];
        if (p + 7 < pe) v7 = h1p[((long long)ebuf[p + 7] << 6) + lane];
        acc += ((v0 + v1) + (v2 + v3)) + ((v4 + v5) + (v6 + v7));
    }
    float deg = (float)(pe - p0);
    bufB[((long long)wid << 6) + lane] = acc * scale[lane] + deg * shiftv[lane];
}

// ---------------------------------------------------------------------------
// Thread-per-node MLP layer 1, in place on bufA (R3-proven: zero DS ops,
// weights via wave-uniform scalar loads, row in VGPRs).
// ---------------------------------------------------------------------------
__global__ __launch_bounds__(64)
void mlp1_kernel(float* hbuf,
                 const float* __restrict__ W1a, const float* __restrict__ B1a,
                 const float* __restrict__ W1b, const float* __restrict__ B1b,
                 int N) {
    int i = blockIdx.x * blockDim.x + threadIdx.x;
    if (i >= N) return;
    long long base = (long long)i * H;
    float h[H], u[H];
#pragma unroll
    for (int f = 0; f < H; ++f) h[f] = hbuf[base + f];
#pragma unroll
    for (int j = 0; j < H; ++j) u[j] = B1a[j];
#pragma unroll
    for (int k = 0; k < H; ++k) {
        float hk = h[k];
#pragma unroll
        for (int j = 0; j < H; ++j) u[j] = fmaf(hk, W1a[k * H + j], u[j]);
    }
#pragma unroll
    for (int j = 0; j < H; ++j) u[j] = fmaxf(u[j], 0.f);
#pragma unroll
    for (int j = 0; j < H; ++j) h[j] = B1b[j];
#pragma unroll
    for (int k = 0; k < H; ++k) {
        float uk = u[k];
#pragma unroll
        for (int j = 0; j < H; ++j) h[j] = fmaf(uk, W1b[k * H + j], h[j]);
    }
#pragma unroll
    for (int j = 0; j < H; ++j) hbuf[base + j] = h[j];
}

// Column sums + sumsq of h1p for batchnorm stats.
__global__ void colsum_kernel(const float* __restrict__ h1p, float* __restrict__ stats, int N) {
    int lane = threadIdx.x & 63;
    int wave = (int)((blockIdx.x * (long long)blockDim.x + threadIdx.x) >> 6);
    int nwaves = (int)(((long long)gridDim.x * blockDim.x) >> 6);
    float s = 0.f, s2 = 0.f;
    for (int r = wave; r < N; r += nwaves) {
        float v = h1p[(long long)r * H + lane];
        s += v;
        s2 += v * v;
    }
    unsafeAtomicAdd(&stats[lane], s);
    unsafeAtomicAdd(&stats[H + lane], s2);
}

__global__ void bn_finalize_kernel(const float* __restrict__ stats,
                                   const float* __restrict__ gamma,
                                   const float* __restrict__ beta,
                                   float* __restrict__ scale, float* __restrict__ shiftv, float n) {
    int f = threadIdx.x;
    if (f >= H) return;
    float mean = stats[f] / n;
    float var = stats[H + f] / n - mean * mean;   // biased, matches jnp.var
    var = fmaxf(var, 0.f);
    float s = gamma[f] * rsqrtf(var + 1e-5f);
    scale[f] = s;
    shiftv[f] = beta[f] - mean * s;
}

// ---------------------------------------------------------------------------
// Thread-per-node MLP layer 2 with folded head: relu(z)@Wf + bf -> out[10].
// ---------------------------------------------------------------------------
__global__ __launch_bounds__(64)
void mlp2_kernel(const float* __restrict__ h1p, const float* __restrict__ scale,
                 const float* __restrict__ shiftv, const float* __restrict__ agg,
                 const float* __restrict__ W2a, const float* __restrict__ B2a,
                 const float* __restrict__ Wf, const float* __restrict__ bf,
                 float* __restrict__ out, int N) {
    int i = blockIdx.x * blockDim.x + threadIdx.x;
    if (i >= N) return;
    long long base = (long long)i * H;
    float h[H], u[H];
#pragma unroll
    for (int f = 0; f < H; ++f)
        h[f] = (h1p[base + f] * scale[f] + shiftv[f]) + agg[base + f];
#pragma unroll
    for (int j = 0; j < H; ++j) u[j] = B2a[j];
#pragma unroll
    for (int k = 0; k < H; ++k) {
        float hk = h[k];
#pragma unroll
        for (int j = 0; j < H; ++j) u[j] = fmaf(hk, W2a[k * H + j], u[j]);
    }
#pragma unroll
    for (int j = 0; j < H; ++j) u[j] = fmaxf(u[j], 0.f);
    float o[10];
#pragma unroll
    for (int c = 0; c < 10; ++c) o[c] = bf[c];
#pragma unroll
    for (int k = 0; k < H; ++k) {
        float uk = u[k];
#pragma unroll
        for (int c = 0; c < 10; ++c) o[c] = fmaf(uk, Wf[k * 10 + c], o[c]);
    }
#pragma unroll
    for (int c = 0; c < 10; ++c) out[(long long)i * 10 + c] = o[c];
}

extern "C" void kernel_launch(void* const* d_in, const int* in_sizes, int n_in,
                              void* d_out, int out_size, void* d_ws, size_t ws_size,
                              hipStream_t stream) {
    const float* x    = (const float*)d_in[0];
    const int*   ei   = (const int*)d_in[1];
    const float* w1a  = (const float*)d_in[2];
    const float* b1a  = (const float*)d_in[3];
    const float* w1b  = (const float*)d_in[4];
    const float* b1b  = (const float*)d_in[5];
    const float* bng  = (const float*)d_in[6];
    const float* bnb  = (const float*)d_in[7];
    const float* w2a  = (const float*)d_in[8];
    const float* b2a  = (const float*)d_in[9];
    const float* w2b  = (const float*)d_in[10];
    const float* b2b  = (const float*)d_in[11];
    const float* linw = (const float*)d_in[12];
    const float* linb = (const float*)d_in[13];

    int N = in_sizes[0] / H;       // 100000
    int E = in_sizes[1] / 2;       // 1600000
    int NB = (N + BKN - 1) / BKN;  // 1563

    // ---- workspace layout (pairs aliases bufB: lifetimes disjoint) ----
    float* ws     = (float*)d_ws;
    float* bufA   = ws;                          // N*H: agg1 -> h1p in place
    float* bufB   = ws + (size_t)N * H;          // N*H: layer-2 aggregate
    int*   pairs  = (int*)bufB;                  // E (dead before gather2 writes bufB)
    float* stats  = ws + 2 * (size_t)N * H;      // 128
    float* scale  = stats + 128;                 // 64
    float* shiftv = stats + 192;                 // 64
    float* Wf     = stats + 256;                 // 640
    float* bf     = Wf + 640;                    // 16
    int*   bcount = (int*)(bf + 16);             // NB
    int*   bbase  = bcount + NB;                 // NB+1
    int*   cursor = bbase + (NB + 1);            // NB*16 (64B-padded)
    int*   rowptr = cursor + NB * 16;            // N+1
    int*   ebuf   = rowptr + (N + 1);            // E

    hipMemsetAsync(stats, 0, 128 * sizeof(float), stream);
    hipMemsetAsync(bcount, 0, (size_t)NB * sizeof(int), stream);

    // CSR build: bucket histogram -> scan -> partition -> per-bucket local CSR
    bhist_kernel<<<256, 256, 0, stream>>>(ei, bcount, E, N, NB);
    bscan_kernel<<<1, 256, 0, stream>>>(bcount, bbase, cursor, rowptr, NB);
    rowptr_tail_kernel<<<1, 64, 0, stream>>>(bbase, rowptr, N, NB);
    part_kernel<<<(E + 255) / 256, 256, 0, stream>>>(ei, cursor, pairs, E, N);
    bucket_csr_kernel<<<NB, 256, 0, stream>>>(pairs, bbase, ebuf, rowptr, N);
    fold_head_kernel<<<3, 256, 0, stream>>>(w2b, b2b, linw, linb, Wf, bf);

    int gblocks = (int)(((long long)N * 64 + 255) / 256);
    gather1_kernel<<<gblocks, 256, 0, stream>>>(x, rowptr, ebuf, bufA, N);
    mlp1_kernel<<<(N + 63) / 64, 64, 0, stream>>>(bufA, w1a, b1a, w1b, b1b, N);
    colsum_kernel<<<512, 256, 0, stream>>>(bufA, stats, N);
    bn_finalize_kernel<<<1, 64, 0, stream>>>(stats, bng, bnb, scale, shiftv, (float)N);

    gather2_kernel<<<gblocks, 256, 0, stream>>>(bufA, scale, shiftv, rowptr, ebuf, bufB, N);
    mlp2_kernel<<<(N + 63) / 64, 64, 0, stream>>>(bufA, scale, shiftv, bufB,
                                                  w2a, b2a, Wf, bf, (float*)d_out, N);
}

// Round 7
// 448.093 us; speedup vs baseline: 3.6960x; 1.3455x over previous
//
#include <hip/hip_runtime.h>

#define H 64
#define CBS 512           // nodes per coarse bucket
#define CB_BITS 9
#define TILE 8192         // edges per partition tile

// ---------------------------------------------------------------------------
// Coarse-bucket histogram over dst>>9, LDS-privatized.
// ---------------------------------------------------------------------------
__global__ __launch_bounds__(256)
void bhist_kernel(const int* __restrict__ ei, int* __restrict__ bcount, int E, int N, int CB) {
    __shared__ int h[256];
    int tid = threadIdx.x;
    h[tid] = 0;
    __syncthreads();
    int stride = gridDim.x * 256;
    for (int e = blockIdx.x * 256 + tid; e < E; e += stride) {
        int s = ei[e];
        int d = ei[E + e];
        if ((unsigned)s < (unsigned)N && (unsigned)d < (unsigned)N)
            atomicAdd(&h[d >> CB_BITS], 1);
    }
    __syncthreads();
    if (tid < CB && h[tid]) atomicAdd(&bcount[tid], h[tid]);
}

// ---------------------------------------------------------------------------
// Exclusive scan of CB (<=256) bucket counts; seeds padded cursors.
// ---------------------------------------------------------------------------
__global__ __launch_bounds__(256)
void bscan_kernel(const int* __restrict__ bcount, int* __restrict__ bbase,
                  int* __restrict__ cursor, int CB) {
    __shared__ int sd[256];
    int t = threadIdx.x;
    int v = (t < CB) ? bcount[t] : 0;
    sd[t] = v; __syncthreads();
    for (int off = 1; off < 256; off <<= 1) {
        int add = (t >= off) ? sd[t - off] : 0;
        __syncthreads();
        sd[t] += add;
        __syncthreads();
    }
    if (t < CB) { bbase[t] = sd[t] - v; cursor[t * 16] = sd[t] - v; }
    if (t == 0) bbase[CB] = sd[255];
}

__global__ void rowptr_tail_kernel(const int* __restrict__ bbase, int* __restrict__ rowptr,
                                   int N, int CB) {
    if (threadIdx.x == 0 && blockIdx.x == 0) rowptr[N] = bbase[CB];
}

// ---------------------------------------------------------------------------
// LDS-staged multi-split partition. Per 8192-edge tile: LDS histogram ->
// LDS scan -> ONE cursor atomic per (tile,bin) -> bin-sort tile in LDS ->
// flush bin-ordered (contiguous runs per bin -> mostly full 64B lines).
// pairs[pos] = src | (dst&511)<<17.
// ---------------------------------------------------------------------------
__global__ __launch_bounds__(256)
void part_staged_kernel(const int* __restrict__ ei, int* __restrict__ gcursor,
                        int* __restrict__ pairs, int E, int N, int CB) {
    __shared__ int sd[256];
    __shared__ int excl[256];
    __shared__ int gbase[256];
    __shared__ int lcur[256];
    __shared__ int stage[TILE];
    __shared__ unsigned char bin8[TILE];
    int t = threadIdx.x;
    int ntiles = (E + TILE - 1) / TILE;
    for (int tile = blockIdx.x; tile < ntiles; tile += gridDim.x) {
        int base = tile * TILE;
        int cnt = min(TILE, E - base);
        sd[t] = 0;                       // sd doubles as histogram first
        __syncthreads();
        for (int i = t; i < cnt; i += 256) {
            int s = ei[base + i];
            int d = ei[E + base + i];
            if ((unsigned)s < (unsigned)N && (unsigned)d < (unsigned)N)
                atomicAdd(&sd[d >> CB_BITS], 1);
        }
        __syncthreads();
        int v = sd[t];                   // my bin count
        __syncthreads();
        // Hillis-Steele inclusive scan of sd
        for (int off = 1; off < 256; off <<= 1) {
            int add = (t >= off) ? sd[t - off] : 0;
            __syncthreads();
            sd[t] += add;
            __syncthreads();
        }
        int ex = sd[t] - v;
        excl[t] = ex;
        lcur[t] = ex;
        if (t < CB && v > 0) gbase[t] = atomicAdd(&gcursor[t * 16], v);
        int tot = sd[255];               // staged entries this tile
        __syncthreads();
        // bin-sort into LDS staging
        for (int i = t; i < cnt; i += 256) {
            int s = ei[base + i];
            int d = ei[E + base + i];
            if ((unsigned)s < (unsigned)N && (unsigned)d < (unsigned)N) {
                int cb = d >> CB_BITS;
                int pos = atomicAdd(&lcur[cb], 1);
                stage[pos] = s | ((d & (CBS - 1)) << 17);
                bin8[pos] = (unsigned char)cb;
            }
        }
        __syncthreads();
        // flush: consecutive i in same bin -> consecutive global positions
        for (int i = t; i < tot; i += 256) {
            int b8 = bin8[i];
            pairs[gbase[b8] + (i - excl[b8])] = stage[i];
        }
        __syncthreads();
    }
}

// ---------------------------------------------------------------------------
// Per-coarse-bucket fine CSR: 512-bin LDS histogram + chunked scan -> rowptr,
// then scatter src into the bucket's contiguous ebuf segment (<=64KB region,
// single-CU -> absorbed by its XCD L2).
// ---------------------------------------------------------------------------
__global__ __launch_bounds__(256)
void bucket_csr_kernel(const int* __restrict__ pairs, const int* __restrict__ bbase,
                       int* __restrict__ ebuf, int* __restrict__ rowptr, int N) {
    __shared__ int hist[CBS];
    __shared__ int cur[CBS];
    __shared__ int sd[256];
    __shared__ int carry_s;
    int b = blockIdx.x;
    int t = threadIdx.x;
    int pb = bbase[b], pe = bbase[b + 1];
    for (int i = t; i < CBS; i += 256) hist[i] = 0;
    if (t == 0) carry_s = 0;
    __syncthreads();
    for (int i = pb + t; i < pe; i += 256)
        atomicAdd(&hist[(pairs[i] >> 17) & (CBS - 1)], 1);
    __syncthreads();
    for (int start = 0; start < CBS; start += 256) {
        int v = hist[start + t];
        sd[t] = v; __syncthreads();
        for (int off = 1; off < 256; off <<= 1) {
            int add = (t >= off) ? sd[t - off] : 0;
            __syncthreads();
            sd[t] += add;
            __syncthreads();
        }
        int ex = sd[t] - v + carry_s;
        cur[start + t] = ex;
        int node = b * CBS + start + t;
        if (node < N) rowptr[node] = pb + ex;
        __syncthreads();
        if (t == 0) carry_s += sd[255];
        __syncthreads();
    }
    for (int i = pb + t; i < pe; i += 256) {
        int p = pairs[i];
        int pos = atomicAdd(&cur[(p >> 17) & (CBS - 1)], 1);
        ebuf[pb + pos] = p & 0x1FFFF;
    }
}

// ---------------------------------------------------------------------------
// Fold linear head into layer-2's second GEMM:
//   (relu(z)@W2b + b2b)@LW + LB == relu(z)@(W2b@LW) + (b2b@LW + LB)
// ---------------------------------------------------------------------------
__global__ void fold_head_kernel(const float* __restrict__ W2b, const float* __restrict__ B2b,
                                 const float* __restrict__ LW, const float* __restrict__ LB,
                                 float* __restrict__ Wf, float* __restrict__ bf) {
    int t = blockIdx.x * blockDim.x + threadIdx.x;
    if (t < 640) {
        int k = t / 10, c = t % 10;
        float a = 0.f;
        for (int m = 0; m < H; ++m) a = fmaf(W2b[k * H + m], LW[m * 10 + c], a);
        Wf[t] = a;
    } else if (t < 650) {
        int c = t - 640;
        float a = LB[c];
        for (int m = 0; m < H; ++m) a = fmaf(B2b[m], LW[m * 10 + c], a);
        bf[c] = a;
    }
}

// ---------------------------------------------------------------------------
// Layer-1 gather: wave per node, lane = feature, 8-wide ILP.
// rowptr/ebuf indices scalarized (wave-uniform) -> s_load, frees VALU.
// ---------------------------------------------------------------------------
__global__ __launch_bounds__(256)
void gather1_kernel(const float* __restrict__ x, const int* __restrict__ rowptr,
                    const int* __restrict__ ebuf, float* __restrict__ bufA, int N) {
    int wid = (int)(((long long)blockIdx.x * blockDim.x + threadIdx.x) >> 6);
    int lane = threadIdx.x & 63;
    if (wid >= N) return;
    int p  = __builtin_amdgcn_readfirstlane(rowptr[wid]);
    int pe = __builtin_amdgcn_readfirstlane(rowptr[wid + 1]);
    float acc = x[((long long)wid << 6) + lane];
    for (; p < pe; p += 8) {
        float v0 = 0.f, v1 = 0.f, v2 = 0.f, v3 = 0.f;
        float v4 = 0.f, v5 = 0.f, v6 = 0.f, v7 = 0.f;
        if (p + 0 < pe) v0 = x[((long long)ebuf[p + 0] << 6) + lane];
        if (p + 1 < pe) v1 = x[((long long)ebuf[p + 1] << 6) + lane];
        if (p + 2 < pe) v2 = x[((long long)ebuf[p + 2] << 6) + lane];
        if (p + 3 < pe) v3 = x[((long long)ebuf[p + 3] << 6) + lane];
        if (p + 4 < pe) v4 = x[((long long)ebuf[p + 4] << 6) + lane];
        if (p + 5 < pe) v5 = x[((long long)ebuf[p + 5] << 6) + lane];
        if (p + 6 < pe) v6 = x[((long long)ebuf[p + 6] << 6) + lane];
        if (p + 7 < pe) v7 = x[((long long)ebuf[p + 7] << 6) + lane];
        acc += ((v0 + v1) + (v2 + v3)) + ((v4 + v5) + (v6 + v7));
    }
    bufA[((long long)wid << 6) + lane] = acc;
}

// ---------------------------------------------------------------------------
// Layer-2 gather with folded BN: bufB = scale*segsum(h1) + deg*shift
// ---------------------------------------------------------------------------
__global__ __launch_bounds__(256)
void gather2_kernel(const float* __restrict__ h1p, const float* __restrict__ scale,
                    const float* __restrict__ shiftv, const int* __restrict__ rowptr,
                    const int* __restrict__ ebuf, float* __restrict__ bufB, int N) {
    int wid = (int)(((long long)blockIdx.x * blockDim.x + threadIdx.x) >> 6);
    int lane = threadIdx.x & 63;
    if (wid >= N) return;
    int p0 = __builtin_amdgcn_readfirstlane(rowptr[wid]);
    int pe = __builtin_amdgcn_readfirstlane(rowptr[wid + 1]);
    int p = p0;
    float acc = 0.f;
    for (; p < pe; p += 8) {
        float v0 = 0.f, v1 = 0.f, v2 = 0.f, v3 = 0.f;
        float v4 = 0.f, v5 = 0.f, v6 = 0.f, v7 = 0.f;
        if (p + 0 < pe) v0 = h1p[((long long)ebuf[p + 0] << 6) + lane];
        if (p + 1 < pe) v1 = h1p[((long long)ebuf[p + 1] << 6) + lane];
        if (p + 2 < pe) v2 = h1p[((long long)ebuf[p + 2] << 6) + lane];
        if (p + 3 < pe) v3 = h1p[((long long)ebuf[p + 3] << 6) + lane];
        if (p + 4 < pe) v4 = h1p[((long long)ebuf[p + 4] << 6) + lane];
        if (p + 5 < pe) v5 = h1p[((long long)ebuf[p + 5] << 6) + lane];
        if (p + 6 < pe) v6 = h1p[((long long)ebuf[p + 6] << 6) + lane];
        if (p + 7 < pe) v7 = h1p[((long long)ebuf[p + 7] << 6) + lane];
        acc += ((v0 + v1) + (v2 + v3)) + ((v4 + v5) + (v6 + v7));
    }
    float deg = (float)(pe - p0);
    bufB[((long long)wid << 6) + lane] = acc * scale[lane] + deg * shiftv[lane];
}

// ---------------------------------------------------------------------------
// Thread-per-node MLP layer 1, in place on bufA (zero DS ops, wave-uniform
// scalar weight loads, row in VGPRs).
// ---------------------------------------------------------------------------
__global__ __launch_bounds__(64)
void mlp1_kernel(float* hbuf,
                 const float* __restrict__ W1a, const float* __restrict__ B1a,
                 const float* __restrict__ W1b, const float* __restrict__ B1b,
                 int N) {
    int i = blockIdx.x * blockDim.x + threadIdx.x;
    if (i >= N) return;
    long long base = (long long)i * H;
    float h[H], u[H];
#pragma unroll
    for (int f = 0; f < H; ++f) h[f] = hbuf[base + f];
#pragma unroll
    for (int j = 0; j < H; ++j) u[j] = B1a[j];
#pragma unroll
    for (int k = 0; k < H; ++k) {
        float hk = h[k];
#pragma unroll
        for (int j = 0; j < H; ++j) u[j] = fmaf(hk, W1a[k * H + j], u[j]);
    }
#pragma unroll
    for (int j = 0; j < H; ++j) u[j] = fmaxf(u[j], 0.f);
#pragma unroll
    for (int j = 0; j < H; ++j) h[j] = B1b[j];
#pragma unroll
    for (int k = 0; k < H; ++k) {
        float uk = u[k];
#pragma unroll
        for (int j = 0; j < H; ++j) h[j] = fmaf(uk, W1b[k * H + j], h[j]);
    }
#pragma unroll
    for (int j = 0; j < H; ++j) hbuf[base + j] = h[j];
}

// Column sums + sumsq of h1p for batchnorm stats.
__global__ void colsum_kernel(const float* __restrict__ h1p, float* __restrict__ stats, int N) {
    int lane = threadIdx.x & 63;
    int wave = (int)((blockIdx.x * (long long)blockDim.x + threadIdx.x) >> 6);
    int nwaves = (int)(((long long)gridDim.x * blockDim.x) >> 6);
    float s = 0.f, s2 = 0.f;
    for (int r = wave; r < N; r += nwaves) {
        float v = h1p[(long long)r * H + lane];
        s += v;
        s2 += v * v;
    }
    unsafeAtomicAdd(&stats[lane], s);
    unsafeAtomicAdd(&stats[H + lane], s2);
}

__global__ void bn_finalize_kernel(const float* __restrict__ stats,
                                   const float* __restrict__ gamma,
                                   const float* __restrict__ beta,
                                   float* __restrict__ scale, float* __restrict__ shiftv, float n) {
    int f = threadIdx.x;
    if (f >= H) return;
    float mean = stats[f] / n;
    float var = stats[H + f] / n - mean * mean;   // biased, matches jnp.var
    var = fmaxf(var, 0.f);
    float s = gamma[f] * rsqrtf(var + 1e-5f);
    scale[f] = s;
    shiftv[f] = beta[f] - mean * s;
}

// ---------------------------------------------------------------------------
// Thread-per-node MLP layer 2 with folded head: relu(z)@Wf + bf -> out[10].
// ---------------------------------------------------------------------------
__global__ __launch_bounds__(64)
void mlp2_kernel(const float* __restrict__ h1p, const float* __restrict__ scale,
                 const float* __restrict__ shiftv, const float* __restrict__ agg,
                 const float* __restrict__ W2a, const float* __restrict__ B2a,
                 const float* __restrict__ Wf, const float* __restrict__ bf,
                 float* __restrict__ out, int N) {
    int i = blockIdx.x * blockDim.x + threadIdx.x;
    if (i >= N) return;
    long long base = (long long)i * H;
    float h[H], u[H];
#pragma unroll
    for (int f = 0; f < H; ++f)
        h[f] = (h1p[base + f] * scale[f] + shiftv[f]) + agg[base + f];
#pragma unroll
    for (int j = 0; j < H; ++j) u[j] = B2a[j];
#pragma unroll
    for (int k = 0; k < H; ++k) {
        float hk = h[k];
#pragma unroll
        for (int j = 0; j < H; ++j) u[j] = fmaf(hk, W2a[k * H + j], u[j]);
    }
#pragma unroll
    for (int j = 0; j < H; ++j) u[j] = fmaxf(u[j], 0.f);
    float o[10];
#pragma unroll
    for (int c = 0; c < 10; ++c) o[c] = bf[c];
#pragma unroll
    for (int k = 0; k < H; ++k) {
        float uk = u[k];
#pragma unroll
        for (int c = 0; c < 10; ++c) o[c] = fmaf(uk, Wf[k * 10 + c], o[c]);
    }
#pragma unroll
    for (int c = 0; c < 10; ++c) out[(long long)i * 10 + c] = o[c];
}

extern "C" void kernel_launch(void* const* d_in, const int* in_sizes, int n_in,
                              void* d_out, int out_size, void* d_ws, size_t ws_size,
                              hipStream_t stream) {
    const float* x    = (const float*)d_in[0];
    const int*   ei   = (const int*)d_in[1];
    const float* w1a  = (const float*)d_in[2];
    const float* b1a  = (const float*)d_in[3];
    const float* w1b  = (const float*)d_in[4];
    const float* b1b  = (const float*)d_in[5];
    const float* bng  = (const float*)d_in[6];
    const float* bnb  = (const float*)d_in[7];
    const float* w2a  = (const float*)d_in[8];
    const float* b2a  = (const float*)d_in[9];
    const float* w2b  = (const float*)d_in[10];
    const float* b2b  = (const float*)d_in[11];
    const float* linw = (const float*)d_in[12];
    const float* linb = (const float*)d_in[13];

    int N = in_sizes[0] / H;       // 100000
    int E = in_sizes[1] / 2;       // 1600000
    int CB = (N + CBS - 1) / CBS;  // 196 coarse buckets (<=256)

    // ---- workspace layout (pairs aliases bufB: lifetimes disjoint) ----
    float* ws     = (float*)d_ws;
    float* bufA   = ws;                          // N*H: agg1 -> h1p in place
    float* bufB   = ws + (size_t)N * H;          // N*H: layer-2 aggregate
    int*   pairs  = (int*)bufB;                  // E (dead before gather2 writes bufB)
    float* stats  = ws + 2 * (size_t)N * H;      // 128
    float* scale  = stats + 128;                 // 64
    float* shiftv = stats + 192;                 // 64
    float* Wf     = stats + 256;                 // 640
    float* bf     = Wf + 640;                    // 16
    int*   bcount = (int*)(bf + 16);             // CB
    int*   bbase  = bcount + 256;                // CB+1
    int*   cursor = bbase + 257;                 // CB*16 (64B-padded)
    int*   rowptr = cursor + 256 * 16;           // N+1
    int*   ebuf   = rowptr + (N + 1);            // E

    hipMemsetAsync(stats, 0, 128 * sizeof(float), stream);
    hipMemsetAsync(bcount, 0, 256 * sizeof(int), stream);

    int ntiles = (E + TILE - 1) / TILE;          // 196

    // CSR build: coarse hist -> scan -> staged multi-split -> per-bucket CSR
    bhist_kernel<<<256, 256, 0, stream>>>(ei, bcount, E, N, CB);
    bscan_kernel<<<1, 256, 0, stream>>>(bcount, bbase, cursor, CB);
    rowptr_tail_kernel<<<1, 64, 0, stream>>>(bbase, rowptr, N, CB);
    part_staged_kernel<<<ntiles, 256, 0, stream>>>(ei, cursor, pairs, E, N, CB);
    bucket_csr_kernel<<<CB, 256, 0, stream>>>(pairs, bbase, ebuf, rowptr, N);
    fold_head_kernel<<<3, 256, 0, stream>>>(w2b, b2b, linw, linb, Wf, bf);

    int gblocks = (int)(((long long)N * 64 + 255) / 256);
    gather1_kernel<<<gblocks, 256, 0, stream>>>(x, rowptr, ebuf, bufA, N);
    mlp1_kernel<<<(N + 63) / 64, 64, 0, stream>>>(bufA, w1a, b1a, w1b, b1b, N);
    colsum_kernel<<<512, 256, 0, stream>>>(bufA, stats, N);
    bn_finalize_kernel<<<1, 64, 0, stream>>>(stats, bng, bnb, scale, shiftv, (float)N);

    gather2_kernel<<<gblocks, 256, 0, stream>>>(bufA, scale, shiftv, rowptr, ebuf, bufB, N);
    mlp2_kernel<<<(N + 63) / 64, 64, 0, stream>>>(bufA, scale, shiftv, bufB,
                                                  w2a, b2a, Wf, bf, (float*)d_out, N);
}

// Round 8
// 407.933 us; speedup vs baseline: 4.0598x; 1.0984x over previous
//
#include <hip/hip_runtime.h>

#define H 64
#define CBS 512           // nodes per coarse bucket
#define CB_BITS 9
#define TILE 8192         // edges per partition tile
#define PAD 65            // LDS row stride (floats): (lane+k)%32 -> 2-way, free

// ---------------------------------------------------------------------------
// Coarse-bucket histogram over dst>>9, LDS-privatized.
// ---------------------------------------------------------------------------
__global__ __launch_bounds__(256)
void bhist_kernel(const int* __restrict__ ei, int* __restrict__ bcount, int E, int N, int CB) {
    __shared__ int h[256];
    int tid = threadIdx.x;
    h[tid] = 0;
    __syncthreads();
    int stride = gridDim.x * 256;
    for (int e = blockIdx.x * 256 + tid; e < E; e += stride) {
        int s = ei[e];
        int d = ei[E + e];
        if ((unsigned)s < (unsigned)N && (unsigned)d < (unsigned)N)
            atomicAdd(&h[d >> CB_BITS], 1);
    }
    __syncthreads();
    if (tid < CB && h[tid]) atomicAdd(&bcount[tid], h[tid]);
}

__global__ __launch_bounds__(256)
void bscan_kernel(const int* __restrict__ bcount, int* __restrict__ bbase,
                  int* __restrict__ cursor, int CB) {
    __shared__ int sd[256];
    int t = threadIdx.x;
    int v = (t < CB) ? bcount[t] : 0;
    sd[t] = v; __syncthreads();
    for (int off = 1; off < 256; off <<= 1) {
        int add = (t >= off) ? sd[t - off] : 0;
        __syncthreads();
        sd[t] += add;
        __syncthreads();
    }
    if (t < CB) { bbase[t] = sd[t] - v; cursor[t * 16] = sd[t] - v; }
    if (t == 0) bbase[CB] = sd[255];
}

__global__ void rowptr_tail_kernel(const int* __restrict__ bbase, int* __restrict__ rowptr,
                                   int N, int CB) {
    if (threadIdx.x == 0 && blockIdx.x == 0) rowptr[N] = bbase[CB];
}

// ---------------------------------------------------------------------------
// LDS-staged multi-split partition (R7-proven).
// ---------------------------------------------------------------------------
__global__ __launch_bounds__(256)
void part_staged_kernel(const int* __restrict__ ei, int* __restrict__ gcursor,
                        int* __restrict__ pairs, int E, int N, int CB) {
    __shared__ int sd[256];
    __shared__ int excl[256];
    __shared__ int gbase[256];
    __shared__ int lcur[256];
    __shared__ int stage[TILE];
    __shared__ unsigned char bin8[TILE];
    int t = threadIdx.x;
    int ntiles = (E + TILE - 1) / TILE;
    for (int tile = blockIdx.x; tile < ntiles; tile += gridDim.x) {
        int base = tile * TILE;
        int cnt = min(TILE, E - base);
        sd[t] = 0;
        __syncthreads();
        for (int i = t; i < cnt; i += 256) {
            int s = ei[base + i];
            int d = ei[E + base + i];
            if ((unsigned)s < (unsigned)N && (unsigned)d < (unsigned)N)
                atomicAdd(&sd[d >> CB_BITS], 1);
        }
        __syncthreads();
        int v = sd[t];
        __syncthreads();
        for (int off = 1; off < 256; off <<= 1) {
            int add = (t >= off) ? sd[t - off] : 0;
            __syncthreads();
            sd[t] += add;
            __syncthreads();
        }
        int ex = sd[t] - v;
        excl[t] = ex;
        lcur[t] = ex;
        if (t < CB && v > 0) gbase[t] = atomicAdd(&gcursor[t * 16], v);
        int tot = sd[255];
        __syncthreads();
        for (int i = t; i < cnt; i += 256) {
            int s = ei[base + i];
            int d = ei[E + base + i];
            if ((unsigned)s < (unsigned)N && (unsigned)d < (unsigned)N) {
                int cb = d >> CB_BITS;
                int pos = atomicAdd(&lcur[cb], 1);
                stage[pos] = s | ((d & (CBS - 1)) << 17);
                bin8[pos] = (unsigned char)cb;
            }
        }
        __syncthreads();
        for (int i = t; i < tot; i += 256) {
            int b8 = bin8[i];
            pairs[gbase[b8] + (i - excl[b8])] = stage[i];
        }
        __syncthreads();
    }
}

// ---------------------------------------------------------------------------
// Per-coarse-bucket fine CSR (R7-proven).
// ---------------------------------------------------------------------------
__global__ __launch_bounds__(256)
void bucket_csr_kernel(const int* __restrict__ pairs, const int* __restrict__ bbase,
                       int* __restrict__ ebuf, int* __restrict__ rowptr, int N) {
    __shared__ int hist[CBS];
    __shared__ int cur[CBS];
    __shared__ int sd[256];
    __shared__ int carry_s;
    int b = blockIdx.x;
    int t = threadIdx.x;
    int pb = bbase[b], pe = bbase[b + 1];
    for (int i = t; i < CBS; i += 256) hist[i] = 0;
    if (t == 0) carry_s = 0;
    __syncthreads();
    for (int i = pb + t; i < pe; i += 256)
        atomicAdd(&hist[(pairs[i] >> 17) & (CBS - 1)], 1);
    __syncthreads();
    for (int start = 0; start < CBS; start += 256) {
        int v = hist[start + t];
        sd[t] = v; __syncthreads();
        for (int off = 1; off < 256; off <<= 1) {
            int add = (t >= off) ? sd[t - off] : 0;
            __syncthreads();
            sd[t] += add;
            __syncthreads();
        }
        int ex = sd[t] - v + carry_s;
        cur[start + t] = ex;
        int node = b * CBS + start + t;
        if (node < N) rowptr[node] = pb + ex;
        __syncthreads();
        if (t == 0) carry_s += sd[255];
        __syncthreads();
    }
    for (int i = pb + t; i < pe; i += 256) {
        int p = pairs[i];
        int pos = atomicAdd(&cur[(p >> 17) & (CBS - 1)], 1);
        ebuf[pb + pos] = p & 0x1FFFF;
    }
}

// ---------------------------------------------------------------------------
// Fold linear head:  (relu(z)@W2b + b2b)@LW + LB == relu(z)@Wf + bf
// ---------------------------------------------------------------------------
__global__ void fold_head_kernel(const float* __restrict__ W2b, const float* __restrict__ B2b,
                                 const float* __restrict__ LW, const float* __restrict__ LB,
                                 float* __restrict__ Wf, float* __restrict__ bf) {
    int t = blockIdx.x * blockDim.x + threadIdx.x;
    if (t < 640) {
        int k = t / 10, c = t % 10;
        float a = 0.f;
        for (int m = 0; m < H; ++m) a = fmaf(W2b[k * H + m], LW[m * 10 + c], a);
        Wf[t] = a;
    } else if (t < 650) {
        int c = t - 640;
        float a = LB[c];
        for (int m = 0; m < H; ++m) a = fmaf(B2b[m], LW[m * 10 + c], a);
        bf[c] = a;
    }
}

// ---------------------------------------------------------------------------
// Layer-1 gather: wave per node, 8-wide unguarded main loop + remainder.
// ---------------------------------------------------------------------------
__global__ __launch_bounds__(256)
void gather1_kernel(const float* __restrict__ x, const int* __restrict__ rowptr,
                    const int* __restrict__ ebuf, float* __restrict__ bufA, int N) {
    int wid = (int)(((long long)blockIdx.x * blockDim.x + threadIdx.x) >> 6);
    int lane = threadIdx.x & 63;
    if (wid >= N) return;
    int p0 = __builtin_amdgcn_readfirstlane(rowptr[wid]);
    int pe = __builtin_amdgcn_readfirstlane(rowptr[wid + 1]);
    float acc = x[((long long)wid << 6) + lane];
    int nfull = (pe - p0) & ~7;
    int p = p0;
    for (; p < p0 + nfull; p += 8) {
        float v0 = x[((long long)ebuf[p + 0] << 6) + lane];
        float v1 = x[((long long)ebuf[p + 1] << 6) + lane];
        float v2 = x[((long long)ebuf[p + 2] << 6) + lane];
        float v3 = x[((long long)ebuf[p + 3] << 6) + lane];
        float v4 = x[((long long)ebuf[p + 4] << 6) + lane];
        float v5 = x[((long long)ebuf[p + 5] << 6) + lane];
        float v6 = x[((long long)ebuf[p + 6] << 6) + lane];
        float v7 = x[((long long)ebuf[p + 7] << 6) + lane];
        acc += ((v0 + v1) + (v2 + v3)) + ((v4 + v5) + (v6 + v7));
    }
    for (; p < pe; ++p) acc += x[((long long)ebuf[p] << 6) + lane];
    bufA[((long long)wid << 6) + lane] = acc;
}

// ---------------------------------------------------------------------------
// Layer-2 gather, now includes self row and full folded BN:
//   bufC = scale*(h1[self] + sum_j h1[j]) + (deg+1)*shift
// ---------------------------------------------------------------------------
__global__ __launch_bounds__(256)
void gather2_kernel(const float* __restrict__ h1p, const float* __restrict__ scale,
                    const float* __restrict__ shiftv, const int* __restrict__ rowptr,
                    const int* __restrict__ ebuf, float* __restrict__ bufC, int N) {
    int wid = (int)(((long long)blockIdx.x * blockDim.x + threadIdx.x) >> 6);
    int lane = threadIdx.x & 63;
    if (wid >= N) return;
    int p0 = __builtin_amdgcn_readfirstlane(rowptr[wid]);
    int pe = __builtin_amdgcn_readfirstlane(rowptr[wid + 1]);
    float acc = h1p[((long long)wid << 6) + lane];   // self
    int nfull = (pe - p0) & ~7;
    int p = p0;
    for (; p < p0 + nfull; p += 8) {
        float v0 = h1p[((long long)ebuf[p + 0] << 6) + lane];
        float v1 = h1p[((long long)ebuf[p + 1] << 6) + lane];
        float v2 = h1p[((long long)ebuf[p + 2] << 6) + lane];
        float v3 = h1p[((long long)ebuf[p + 3] << 6) + lane];
        float v4 = h1p[((long long)ebuf[p + 4] << 6) + lane];
        float v5 = h1p[((long long)ebuf[p + 5] << 6) + lane];
        float v6 = h1p[((long long)ebuf[p + 6] << 6) + lane];
        float v7 = h1p[((long long)ebuf[p + 7] << 6) + lane];
        acc += ((v0 + v1) + (v2 + v3)) + ((v4 + v5) + (v6 + v7));
    }
    for (; p < pe; ++p) acc += h1p[((long long)ebuf[p] << 6) + lane];
    float degp1 = (float)(pe - p0 + 1);
    bufC[((long long)wid << 6) + lane] = acc * scale[lane] + degp1 * shiftv[lane];
}

// ---------------------------------------------------------------------------
// MLP layer 1 + fused BN stats. 256 threads; each wave stages its 64 node
// rows into padded LDS (coalesced), computes thread-per-node MLP (h via
// ds_read, weights via wave-uniform s_load, u/h1 in VGPRs), writes h1 back
// through LDS (coalesced store), and column-sums the tile for BN stats.
// No early returns (barrier at the end); all memory ops guarded.
// ---------------------------------------------------------------------------
__global__ __launch_bounds__(256)
void mlp1_kernel(const float* __restrict__ bufA, float* __restrict__ h1p,
                 const float* __restrict__ W1a, const float* __restrict__ B1a,
                 const float* __restrict__ W1b, const float* __restrict__ B1b,
                 float* __restrict__ stats, int N) {
    __shared__ float st[4][64 * PAD];     // 66.56 KB
    __shared__ float red[2][4][64];
    int t = threadIdx.x, wv = t >> 6, lane = t & 63;
    int node0 = (blockIdx.x * 4 + wv) * 64;
    float* S = st[wv];

    // stage 64 rows, coalesced; zero rows beyond N
#pragma unroll 8
    for (int r = 0; r < 64; ++r) {
        float v = bufA[((long long)(node0 + r) << 6) + lane];
        S[r * PAD + lane] = (node0 + r < N) ? v : 0.f;
    }
    bool valid = (node0 + lane < N);

    float u[H];
#pragma unroll
    for (int j = 0; j < H; ++j) u[j] = B1a[j];
#pragma unroll
    for (int k = 0; k < H; ++k) {
        float hk = S[lane * PAD + k];
#pragma unroll
        for (int j = 0; j < H; ++j) u[j] = fmaf(hk, W1a[k * H + j], u[j]);
    }
#pragma unroll
    for (int j = 0; j < H; ++j) u[j] = fmaxf(u[j], 0.f);
    float h1[H];
#pragma unroll
    for (int j = 0; j < H; ++j) h1[j] = B1b[j];
#pragma unroll
    for (int k = 0; k < H; ++k) {
        float uk = u[k];
#pragma unroll
        for (int j = 0; j < H; ++j) h1[j] = fmaf(uk, W1b[k * H + j], h1[j]);
    }
    // write tile back (zero for invalid nodes so colsums stay clean)
#pragma unroll
    for (int j = 0; j < H; ++j) S[lane * PAD + j] = valid ? h1[j] : 0.f;

    // coalesced h1p store
#pragma unroll 8
    for (int r = 0; r < 64; ++r) {
        if (node0 + r < N)
            h1p[((long long)(node0 + r) << 6) + lane] = S[r * PAD + lane];
    }
    // per-wave column sums (lane = feature)
    float s = 0.f, s2 = 0.f;
#pragma unroll 8
    for (int r = 0; r < 64; ++r) {
        float v = S[r * PAD + lane];
        s += v;
        s2 = fmaf(v, v, s2);
    }
    red[0][wv][lane] = s;
    red[1][wv][lane] = s2;
    __syncthreads();
    if (wv == 0) {
        float ts  = (red[0][0][lane] + red[0][1][lane]) + (red[0][2][lane] + red[0][3][lane]);
        float ts2 = (red[1][0][lane] + red[1][1][lane]) + (red[1][2][lane] + red[1][3][lane]);
        unsafeAtomicAdd(&stats[lane], ts);
        unsafeAtomicAdd(&stats[H + lane], ts2);
    }
}

__global__ void bn_finalize_kernel(const float* __restrict__ stats,
                                   const float* __restrict__ gamma,
                                   const float* __restrict__ beta,
                                   float* __restrict__ scale, float* __restrict__ shiftv, float n) {
    int f = threadIdx.x;
    if (f >= H) return;
    float mean = stats[f] / n;
    float var = stats[H + f] / n - mean * mean;   // biased, matches jnp.var
    var = fmaxf(var, 0.f);
    float s = gamma[f] * rsqrtf(var + 1e-5f);
    scale[f] = s;
    shiftv[f] = beta[f] - mean * s;
}

// ---------------------------------------------------------------------------
// MLP layer 2 + folded head. Input bufC already holds full h_in2.
// Same staging pattern; 10-wide output staged through LDS (pad 11).
// ---------------------------------------------------------------------------
__global__ __launch_bounds__(256)
void mlp2_kernel(const float* __restrict__ bufC,
                 const float* __restrict__ W2a, const float* __restrict__ B2a,
                 const float* __restrict__ Wf, const float* __restrict__ bf,
                 float* __restrict__ out, int N) {
    __shared__ float st[4][64 * PAD];     // 66.56 KB
    __shared__ float ost[4][64 * 11];     // 11.26 KB
    int t = threadIdx.x, wv = t >> 6, lane = t & 63;
    int node0 = (blockIdx.x * 4 + wv) * 64;
    float* S = st[wv];
    float* O = ost[wv];

#pragma unroll 8
    for (int r = 0; r < 64; ++r) {
        float v = bufC[((long long)(node0 + r) << 6) + lane];
        S[r * PAD + lane] = (node0 + r < N) ? v : 0.f;
    }
    float u[H];
#pragma unroll
    for (int j = 0; j < H; ++j) u[j] = B2a[j];
#pragma unroll
    for (int k = 0; k < H; ++k) {
        float hk = S[lane * PAD + k];
#pragma unroll
        for (int j = 0; j < H; ++j) u[j] = fmaf(hk, W2a[k * H + j], u[j]);
    }
#pragma unroll
    for (int j = 0; j < H; ++j) u[j] = fmaxf(u[j], 0.f);
    float o[10];
#pragma unroll
    for (int c = 0; c < 10; ++c) o[c] = bf[c];
#pragma unroll
    for (int k = 0; k < H; ++k) {
        float uk = u[k];
#pragma unroll
        for (int c = 0; c < 10; ++c) o[c] = fmaf(uk, Wf[k * 10 + c], o[c]);
    }
#pragma unroll
    for (int c = 0; c < 10; ++c) O[lane * 11 + c] = o[c];
    // coalesced out store: 640 contiguous floats per wave
    for (int i = lane; i < 640; i += 64) {
        int r = i / 10, c = i - r * 10;
        if (node0 + r < N)
            out[(long long)(node0 + r) * 10 + c] = O[r * 11 + c];
    }
}

extern "C" void kernel_launch(void* const* d_in, const int* in_sizes, int n_in,
                              void* d_out, int out_size, void* d_ws, size_t ws_size,
                              hipStream_t stream) {
    const float* x    = (const float*)d_in[0];
    const int*   ei   = (const int*)d_in[1];
    const float* w1a  = (const float*)d_in[2];
    const float* b1a  = (const float*)d_in[3];
    const float* w1b  = (const float*)d_in[4];
    const float* b1b  = (const float*)d_in[5];
    const float* bng  = (const float*)d_in[6];
    const float* bnb  = (const float*)d_in[7];
    const float* w2a  = (const float*)d_in[8];
    const float* b2a  = (const float*)d_in[9];
    const float* w2b  = (const float*)d_in[10];
    const float* b2b  = (const float*)d_in[11];
    const float* linw = (const float*)d_in[12];
    const float* linb = (const float*)d_in[13];

    int N = in_sizes[0] / H;       // 100000
    int E = in_sizes[1] / 2;       // 1600000
    int CB = (N + CBS - 1) / CBS;  // 196 coarse buckets

    // ---- workspace layout (pairs aliases bufC: lifetimes disjoint) ----
    float* ws     = (float*)d_ws;
    float* bufA   = ws;                          // N*H: agg1 -> h1p in place
    float* bufC   = ws + (size_t)N * H;          // N*H: full layer-2 input
    int*   pairs  = (int*)bufC;                  // E (dead before gather2 writes bufC)
    float* stats  = ws + 2 * (size_t)N * H;      // 128
    float* scale  = stats + 128;                 // 64
    float* shiftv = stats + 192;                 // 64
    float* Wf     = stats + 256;                 // 640
    float* bf     = Wf + 640;                    // 16
    int*   bcount = (int*)(bf + 16);             // 256
    int*   bbase  = bcount + 256;                // 257
    int*   cursor = bbase + 257;                 // 256*16
    int*   rowptr = cursor + 256 * 16;           // N+1
    int*   ebuf   = rowptr + (N + 1);            // E

    hipMemsetAsync(stats, 0, 128 * sizeof(float), stream);
    hipMemsetAsync(bcount, 0, 256 * sizeof(int), stream);

    int ntiles = (E + TILE - 1) / TILE;

    bhist_kernel<<<256, 256, 0, stream>>>(ei, bcount, E, N, CB);
    bscan_kernel<<<1, 256, 0, stream>>>(bcount, bbase, cursor, CB);
    rowptr_tail_kernel<<<1, 64, 0, stream>>>(bbase, rowptr, N, CB);
    part_staged_kernel<<<ntiles, 256, 0, stream>>>(ei, cursor, pairs, E, N, CB);
    bucket_csr_kernel<<<CB, 256, 0, stream>>>(pairs, bbase, ebuf, rowptr, N);
    fold_head_kernel<<<3, 256, 0, stream>>>(w2b, b2b, linw, linb, Wf, bf);

    int gblocks = (int)(((long long)N * 64 + 255) / 256);
    int mblocks = (N + 255) / 256;
    gather1_kernel<<<gblocks, 256, 0, stream>>>(x, rowptr, ebuf, bufA, N);
    mlp1_kernel<<<mblocks, 256, 0, stream>>>(bufA, bufA, w1a, b1a, w1b, b1b, stats, N);
    bn_finalize_kernel<<<1, 64, 0, stream>>>(stats, bng, bnb, scale, shiftv, (float)N);

    gather2_kernel<<<gblocks, 256, 0, stream>>>(bufA, scale, shiftv, rowptr, ebuf, bufC, N);
    mlp2_kernel<<<mblocks, 256, 0, stream>>>(bufC, w2a, b2a, Wf, bf, (float*)d_out, N);
}

// Round 9
// 398.539 us; speedup vs baseline: 4.1555x; 1.0236x over previous
//
#include <hip/hip_runtime.h>

#define H 64
#define CBS 512           // nodes per coarse bucket
#define CB_BITS 9
#define TILE 8192         // edges per partition tile
#define PAD 65            // LDS row stride (floats): 2-way bank aliasing, free

// ---------------------------------------------------------------------------
// Coarse-bucket histogram over dst>>9, LDS-privatized.
// ---------------------------------------------------------------------------
__global__ __launch_bounds__(256)
void bhist_kernel(const int* __restrict__ ei, int* __restrict__ bcount, int E, int N, int CB) {
    __shared__ int h[256];
    int tid = threadIdx.x;
    h[tid] = 0;
    __syncthreads();
    int stride = gridDim.x * 256;
    for (int e = blockIdx.x * 256 + tid; e < E; e += stride) {
        int s = ei[e];
        int d = ei[E + e];
        if ((unsigned)s < (unsigned)N && (unsigned)d < (unsigned)N)
            atomicAdd(&h[d >> CB_BITS], 1);
    }
    __syncthreads();
    if (tid < CB && h[tid]) atomicAdd(&bcount[tid], h[tid]);
}

__global__ __launch_bounds__(256)
void bscan_kernel(const int* __restrict__ bcount, int* __restrict__ bbase,
                  int* __restrict__ cursor, int CB) {
    __shared__ int sd[256];
    int t = threadIdx.x;
    int v = (t < CB) ? bcount[t] : 0;
    sd[t] = v; __syncthreads();
    for (int off = 1; off < 256; off <<= 1) {
        int add = (t >= off) ? sd[t - off] : 0;
        __syncthreads();
        sd[t] += add;
        __syncthreads();
    }
    if (t < CB) { bbase[t] = sd[t] - v; cursor[t * 16] = sd[t] - v; }
    if (t == 0) bbase[CB] = sd[255];
}

__global__ void rowptr_tail_kernel(const int* __restrict__ bbase, int* __restrict__ rowptr,
                                   int N, int CB) {
    if (threadIdx.x == 0 && blockIdx.x == 0) rowptr[N] = bbase[CB];
}

// ---------------------------------------------------------------------------
// LDS-staged multi-split partition (R7-proven).
// ---------------------------------------------------------------------------
__global__ __launch_bounds__(256)
void part_staged_kernel(const int* __restrict__ ei, int* __restrict__ gcursor,
                        int* __restrict__ pairs, int E, int N, int CB) {
    __shared__ int sd[256];
    __shared__ int excl[256];
    __shared__ int gbase[256];
    __shared__ int lcur[256];
    __shared__ int stage[TILE];
    __shared__ unsigned char bin8[TILE];
    int t = threadIdx.x;
    int ntiles = (E + TILE - 1) / TILE;
    for (int tile = blockIdx.x; tile < ntiles; tile += gridDim.x) {
        int base = tile * TILE;
        int cnt = min(TILE, E - base);
        sd[t] = 0;
        __syncthreads();
        for (int i = t; i < cnt; i += 256) {
            int s = ei[base + i];
            int d = ei[E + base + i];
            if ((unsigned)s < (unsigned)N && (unsigned)d < (unsigned)N)
                atomicAdd(&sd[d >> CB_BITS], 1);
        }
        __syncthreads();
        int v = sd[t];
        __syncthreads();
        for (int off = 1; off < 256; off <<= 1) {
            int add = (t >= off) ? sd[t - off] : 0;
            __syncthreads();
            sd[t] += add;
            __syncthreads();
        }
        int ex = sd[t] - v;
        excl[t] = ex;
        lcur[t] = ex;
        if (t < CB && v > 0) gbase[t] = atomicAdd(&gcursor[t * 16], v);
        int tot = sd[255];
        __syncthreads();
        for (int i = t; i < cnt; i += 256) {
            int s = ei[base + i];
            int d = ei[E + base + i];
            if ((unsigned)s < (unsigned)N && (unsigned)d < (unsigned)N) {
                int cb = d >> CB_BITS;
                int pos = atomicAdd(&lcur[cb], 1);
                stage[pos] = s | ((d & (CBS - 1)) << 17);
                bin8[pos] = (unsigned char)cb;
            }
        }
        __syncthreads();
        for (int i = t; i < tot; i += 256) {
            int b8 = bin8[i];
            pairs[gbase[b8] + (i - excl[b8])] = stage[i];
        }
        __syncthreads();
    }
}

// ---------------------------------------------------------------------------
// Per-coarse-bucket fine CSR (R7-proven).
// ---------------------------------------------------------------------------
__global__ __launch_bounds__(256)
void bucket_csr_kernel(const int* __restrict__ pairs, const int* __restrict__ bbase,
                       int* __restrict__ ebuf, int* __restrict__ rowptr, int N) {
    __shared__ int hist[CBS];
    __shared__ int cur[CBS];
    __shared__ int sd[256];
    __shared__ int carry_s;
    int b = blockIdx.x;
    int t = threadIdx.x;
    int pb = bbase[b], pe = bbase[b + 1];
    for (int i = t; i < CBS; i += 256) hist[i] = 0;
    if (t == 0) carry_s = 0;
    __syncthreads();
    for (int i = pb + t; i < pe; i += 256)
        atomicAdd(&hist[(pairs[i] >> 17) & (CBS - 1)], 1);
    __syncthreads();
    for (int start = 0; start < CBS; start += 256) {
        int v = hist[start + t];
        sd[t] = v; __syncthreads();
        for (int off = 1; off < 256; off <<= 1) {
            int add = (t >= off) ? sd[t - off] : 0;
            __syncthreads();
            sd[t] += add;
            __syncthreads();
        }
        int ex = sd[t] - v + carry_s;
        cur[start + t] = ex;
        int node = b * CBS + start + t;
        if (node < N) rowptr[node] = pb + ex;
        __syncthreads();
        if (t == 0) carry_s += sd[255];
        __syncthreads();
    }
    for (int i = pb + t; i < pe; i += 256) {
        int p = pairs[i];
        int pos = atomicAdd(&cur[(p >> 17) & (CBS - 1)], 1);
        ebuf[pb + pos] = p & 0x1FFFF;
    }
}

// ---------------------------------------------------------------------------
// Fold linear head:  (relu(z)@W2b + b2b)@LW + LB == relu(z)@Wf + bf
// ---------------------------------------------------------------------------
__global__ void fold_head_kernel(const float* __restrict__ W2b, const float* __restrict__ B2b,
                                 const float* __restrict__ LW, const float* __restrict__ LB,
                                 float* __restrict__ Wf, float* __restrict__ bf) {
    int t = blockIdx.x * blockDim.x + threadIdx.x;
    if (t < 640) {
        int k = t / 10, c = t % 10;
        float a = 0.f;
        for (int m = 0; m < H; ++m) a = fmaf(W2b[k * H + m], LW[m * 10 + c], a);
        Wf[t] = a;
    } else if (t < 650) {
        int c = t - 640;
        float a = LB[c];
        for (int m = 0; m < H; ++m) a = fmaf(B2b[m], LW[m * 10 + c], a);
        bf[c] = a;
    }
}

// ---------------------------------------------------------------------------
// Layer-1 gather: wave per node, 8-wide unguarded main loop + remainder.
// ---------------------------------------------------------------------------
__global__ __launch_bounds__(256)
void gather1_kernel(const float* __restrict__ x, const int* __restrict__ rowptr,
                    const int* __restrict__ ebuf, float* __restrict__ bufA, int N) {
    int wid = (int)(((long long)blockIdx.x * blockDim.x + threadIdx.x) >> 6);
    int lane = threadIdx.x & 63;
    if (wid >= N) return;
    int p0 = __builtin_amdgcn_readfirstlane(rowptr[wid]);
    int pe = __builtin_amdgcn_readfirstlane(rowptr[wid + 1]);
    float acc = x[((long long)wid << 6) + lane];
    int nfull = (pe - p0) & ~7;
    int p = p0;
    for (; p < p0 + nfull; p += 8) {
        float v0 = x[((long long)ebuf[p + 0] << 6) + lane];
        float v1 = x[((long long)ebuf[p + 1] << 6) + lane];
        float v2 = x[((long long)ebuf[p + 2] << 6) + lane];
        float v3 = x[((long long)ebuf[p + 3] << 6) + lane];
        float v4 = x[((long long)ebuf[p + 4] << 6) + lane];
        float v5 = x[((long long)ebuf[p + 5] << 6) + lane];
        float v6 = x[((long long)ebuf[p + 6] << 6) + lane];
        float v7 = x[((long long)ebuf[p + 7] << 6) + lane];
        acc += ((v0 + v1) + (v2 + v3)) + ((v4 + v5) + (v6 + v7));
    }
    for (; p < pe; ++p) acc += x[((long long)ebuf[p] << 6) + lane];
    bufA[((long long)wid << 6) + lane] = acc;
}

// ---------------------------------------------------------------------------
// Layer-2 gather with self row and full folded BN:
//   bufC = scale*(h1[self] + sum_j h1[j]) + (deg+1)*shift
// ---------------------------------------------------------------------------
__global__ __launch_bounds__(256)
void gather2_kernel(const float* __restrict__ h1p, const float* __restrict__ scale,
                    const float* __restrict__ shiftv, const int* __restrict__ rowptr,
                    const int* __restrict__ ebuf, float* __restrict__ bufC, int N) {
    int wid = (int)(((long long)blockIdx.x * blockDim.x + threadIdx.x) >> 6);
    int lane = threadIdx.x & 63;
    if (wid >= N) return;
    int p0 = __builtin_amdgcn_readfirstlane(rowptr[wid]);
    int pe = __builtin_amdgcn_readfirstlane(rowptr[wid + 1]);
    float acc = h1p[((long long)wid << 6) + lane];   // self
    int nfull = (pe - p0) & ~7;
    int p = p0;
    for (; p < p0 + nfull; p += 8) {
        float v0 = h1p[((long long)ebuf[p + 0] << 6) + lane];
        float v1 = h1p[((long long)ebuf[p + 1] << 6) + lane];
        float v2 = h1p[((long long)ebuf[p + 2] << 6) + lane];
        float v3 = h1p[((long long)ebuf[p + 3] << 6) + lane];
        float v4 = h1p[((long long)ebuf[p + 4] << 6) + lane];
        float v5 = h1p[((long long)ebuf[p + 5] << 6) + lane];
        float v6 = h1p[((long long)ebuf[p + 6] << 6) + lane];
        float v7 = h1p[((long long)ebuf[p + 7] << 6) + lane];
        acc += ((v0 + v1) + (v2 + v3)) + ((v4 + v5) + (v6 + v7));
    }
    for (; p < pe; ++p) acc += h1p[((long long)ebuf[p] << 6) + lane];
    float degp1 = (float)(pe - p0 + 1);
    bufC[((long long)wid << 6) + lane] = acc * scale[lane] + degp1 * shiftv[lane];
}

// ---------------------------------------------------------------------------
// MLP layer 1 + fused BN stats. LDS-staged tile (R8-proven data path), but
// k-loops ROLLED (#pragma unroll 1): ~300B loop body stays I-cache resident;
// per iter: 1 ds_read_b32 + wave-uniform s_load of weight row + 64 v_fmac.
// ---------------------------------------------------------------------------
__global__ __launch_bounds__(256)
void mlp1_kernel(const float* __restrict__ bufA, float* __restrict__ h1p,
                 const float* __restrict__ W1a, const float* __restrict__ B1a,
                 const float* __restrict__ W1b, const float* __restrict__ B1b,
                 float* __restrict__ stats, int N) {
    __shared__ float st[4][64 * PAD];     // 66.56 KB
    __shared__ float red[2][4][64];
    int t = threadIdx.x, wv = t >> 6, lane = t & 63;
    int node0 = (blockIdx.x * 4 + wv) * 64;
    float* S = st[wv];

#pragma unroll 8
    for (int r = 0; r < 64; ++r) {
        float v = bufA[((long long)(node0 + r) << 6) + lane];
        S[r * PAD + lane] = (node0 + r < N) ? v : 0.f;
    }
    bool valid = (node0 + lane < N);

    float u[H];
#pragma unroll
    for (int j = 0; j < H; ++j) u[j] = B1a[j];
#pragma unroll 1
    for (int k = 0; k < H; ++k) {
        float hk = S[lane * PAD + k];
#pragma unroll
        for (int j = 0; j < H; ++j) u[j] = fmaf(hk, W1a[k * H + j], u[j]);
    }
#pragma unroll
    for (int j = 0; j < H; ++j) u[j] = fmaxf(u[j], 0.f);
    float h1[H];
#pragma unroll
    for (int j = 0; j < H; ++j) h1[j] = B1b[j];
#pragma unroll 1
    for (int k = 0; k < H; ++k) {
        float uk = u[k];
#pragma unroll
        for (int j = 0; j < H; ++j) h1[j] = fmaf(uk, W1b[k * H + j], h1[j]);
    }
#pragma unroll
    for (int j = 0; j < H; ++j) S[lane * PAD + j] = valid ? h1[j] : 0.f;

#pragma unroll 8
    for (int r = 0; r < 64; ++r) {
        if (node0 + r < N)
            h1p[((long long)(node0 + r) << 6) + lane] = S[r * PAD + lane];
    }
    float s = 0.f, s2 = 0.f;
#pragma unroll 8
    for (int r = 0; r < 64; ++r) {
        float v = S[r * PAD + lane];
        s += v;
        s2 = fmaf(v, v, s2);
    }
    red[0][wv][lane] = s;
    red[1][wv][lane] = s2;
    __syncthreads();
    if (wv == 0) {
        float ts  = (red[0][0][lane] + red[0][1][lane]) + (red[0][2][lane] + red[0][3][lane]);
        float ts2 = (red[1][0][lane] + red[1][1][lane]) + (red[1][2][lane] + red[1][3][lane]);
        unsafeAtomicAdd(&stats[lane], ts);
        unsafeAtomicAdd(&stats[H + lane], ts2);
    }
}

__global__ void bn_finalize_kernel(const float* __restrict__ stats,
                                   const float* __restrict__ gamma,
                                   const float* __restrict__ beta,
                                   float* __restrict__ scale, float* __restrict__ shiftv, float n) {
    int f = threadIdx.x;
    if (f >= H) return;
    float mean = stats[f] / n;
    float var = stats[H + f] / n - mean * mean;   // biased, matches jnp.var
    var = fmaxf(var, 0.f);
    float s = gamma[f] * rsqrtf(var + 1e-5f);
    scale[f] = s;
    shiftv[f] = beta[f] - mean * s;
}

// ---------------------------------------------------------------------------
// MLP layer 2 + folded head, k-loops rolled.
// ---------------------------------------------------------------------------
__global__ __launch_bounds__(256)
void mlp2_kernel(const float* __restrict__ bufC,
                 const float* __restrict__ W2a, const float* __restrict__ B2a,
                 const float* __restrict__ Wf, const float* __restrict__ bf,
                 float* __restrict__ out, int N) {
    __shared__ float st[4][64 * PAD];     // 66.56 KB
    __shared__ float ost[4][64 * 11];     // 11.26 KB
    int t = threadIdx.x, wv = t >> 6, lane = t & 63;
    int node0 = (blockIdx.x * 4 + wv) * 64;
    float* S = st[wv];
    float* O = ost[wv];

#pragma unroll 8
    for (int r = 0; r < 64; ++r) {
        float v = bufC[((long long)(node0 + r) << 6) + lane];
        S[r * PAD + lane] = (node0 + r < N) ? v : 0.f;
    }
    float u[H];
#pragma unroll
    for (int j = 0; j < H; ++j) u[j] = B2a[j];
#pragma unroll 1
    for (int k = 0; k < H; ++k) {
        float hk = S[lane * PAD + k];
#pragma unroll
        for (int j = 0; j < H; ++j) u[j] = fmaf(hk, W2a[k * H + j], u[j]);
    }
#pragma unroll
    for (int j = 0; j < H; ++j) u[j] = fmaxf(u[j], 0.f);
    float o[10];
#pragma unroll
    for (int c = 0; c < 10; ++c) o[c] = bf[c];
#pragma unroll 1
    for (int k = 0; k < H; ++k) {
        float uk = u[k];
#pragma unroll
        for (int c = 0; c < 10; ++c) o[c] = fmaf(uk, Wf[k * 10 + c], o[c]);
    }
#pragma unroll
    for (int c = 0; c < 10; ++c) O[lane * 11 + c] = o[c];
    for (int i = lane; i < 640; i += 64) {
        int r = i / 10, c = i - r * 10;
        if (node0 + r < N)
            out[(long long)(node0 + r) * 10 + c] = O[r * 11 + c];
    }
}

extern "C" void kernel_launch(void* const* d_in, const int* in_sizes, int n_in,
                              void* d_out, int out_size, void* d_ws, size_t ws_size,
                              hipStream_t stream) {
    const float* x    = (const float*)d_in[0];
    const int*   ei   = (const int*)d_in[1];
    const float* w1a  = (const float*)d_in[2];
    const float* b1a  = (const float*)d_in[3];
    const float* w1b  = (const float*)d_in[4];
    const float* b1b  = (const float*)d_in[5];
    const float* bng  = (const float*)d_in[6];
    const float* bnb  = (const float*)d_in[7];
    const float* w2a  = (const float*)d_in[8];
    const float* b2a  = (const float*)d_in[9];
    const float* w2b  = (const float*)d_in[10];
    const float* b2b  = (const float*)d_in[11];
    const float* linw = (const float*)d_in[12];
    const float* linb = (const float*)d_in[13];

    int N = in_sizes[0] / H;       // 100000
    int E = in_sizes[1] / 2;       // 1600000
    int CB = (N + CBS - 1) / CBS;  // 196 coarse buckets

    // ---- workspace layout (pairs aliases bufC: lifetimes disjoint) ----
    float* ws     = (float*)d_ws;
    float* bufA   = ws;                          // N*H: agg1 -> h1p in place
    float* bufC   = ws + (size_t)N * H;          // N*H: full layer-2 input
    int*   pairs  = (int*)bufC;                  // E (dead before gather2 writes bufC)
    float* stats  = ws + 2 * (size_t)N * H;      // 128
    float* scale  = stats + 128;                 // 64
    float* shiftv = stats + 192;                 // 64
    float* Wf     = stats + 256;                 // 640
    float* bf     = Wf + 640;                    // 16
    int*   bcount = (int*)(bf + 16);             // 256
    int*   bbase  = bcount + 256;                // 257
    int*   cursor = bbase + 257;                 // 256*16
    int*   rowptr = cursor + 256 * 16;           // N+1
    int*   ebuf   = rowptr + (N + 1);            // E

    hipMemsetAsync(stats, 0, 128 * sizeof(float), stream);
    hipMemsetAsync(bcount, 0, 256 * sizeof(int), stream);

    int ntiles = (E + TILE - 1) / TILE;

    bhist_kernel<<<256, 256, 0, stream>>>(ei, bcount, E, N, CB);
    bscan_kernel<<<1, 256, 0, stream>>>(bcount, bbase, cursor, CB);
    rowptr_tail_kernel<<<1, 64, 0, stream>>>(bbase, rowptr, N, CB);
    part_staged_kernel<<<ntiles, 256, 0, stream>>>(ei, cursor, pairs, E, N, CB);
    bucket_csr_kernel<<<CB, 256, 0, stream>>>(pairs, bbase, ebuf, rowptr, N);
    fold_head_kernel<<<3, 256, 0, stream>>>(w2b, b2b, linw, linb, Wf, bf);

    int gblocks = (int)(((long long)N * 64 + 255) / 256);
    int mblocks = (N + 255) / 256;
    gather1_kernel<<<gblocks, 256, 0, stream>>>(x, rowptr, ebuf, bufA, N);
    mlp1_kernel<<<mblocks, 256, 0, stream>>>(bufA, bufA, w1a, b1a, w1b, b1b, stats, N);
    bn_finalize_kernel<<<1, 64, 0, stream>>>(stats, bng, bnb, scale, shiftv, (float)N);

    gather2_kernel<<<gblocks, 256, 0, stream>>>(bufA, scale, shiftv, rowptr, ebuf, bufC, N);
    mlp2_kernel<<<mblocks, 256, 0, stream>>>(bufC, w2a, b2a, Wf, bf, (float*)d_out, N);
}

// Round 10
// 378.224 us; speedup vs baseline: 4.3787x; 1.0537x over previous
//
#include <hip/hip_runtime.h>

#define H 64
#define CBS 512           // nodes per coarse bucket
#define CB_BITS 9
#define TILE 8192         // edges per partition tile
#define PAD 65            // LDS row stride (floats): 2-way bank aliasing, free

// ---------------------------------------------------------------------------
// Coarse-bucket histogram over dst>>9, LDS-privatized.
// ---------------------------------------------------------------------------
__global__ __launch_bounds__(256)
void bhist_kernel(const int* __restrict__ ei, int* __restrict__ bcount, int E, int N, int CB) {
    __shared__ int h[256];
    int tid = threadIdx.x;
    h[tid] = 0;
    __syncthreads();
    int stride = gridDim.x * 256;
    for (int e = blockIdx.x * 256 + tid; e < E; e += stride) {
        int s = ei[e];
        int d = ei[E + e];
        if ((unsigned)s < (unsigned)N && (unsigned)d < (unsigned)N)
            atomicAdd(&h[d >> CB_BITS], 1);
    }
    __syncthreads();
    if (tid < CB && h[tid]) atomicAdd(&bcount[tid], h[tid]);
}

__global__ __launch_bounds__(256)
void bscan_kernel(const int* __restrict__ bcount, int* __restrict__ bbase,
                  int* __restrict__ cursor, int CB) {
    __shared__ int sd[256];
    int t = threadIdx.x;
    int v = (t < CB) ? bcount[t] : 0;
    sd[t] = v; __syncthreads();
    for (int off = 1; off < 256; off <<= 1) {
        int add = (t >= off) ? sd[t - off] : 0;
        __syncthreads();
        sd[t] += add;
        __syncthreads();
    }
    if (t < CB) { bbase[t] = sd[t] - v; cursor[t * 16] = sd[t] - v; }
    if (t == 0) bbase[CB] = sd[255];
}

__global__ void rowptr_tail_kernel(const int* __restrict__ bbase, int* __restrict__ rowptr,
                                   int N, int CB) {
    if (threadIdx.x == 0 && blockIdx.x == 0) rowptr[N] = bbase[CB];
}

// ---------------------------------------------------------------------------
// LDS-staged multi-split partition (R7-proven).
// ---------------------------------------------------------------------------
__global__ __launch_bounds__(256)
void part_staged_kernel(const int* __restrict__ ei, int* __restrict__ gcursor,
                        int* __restrict__ pairs, int E, int N, int CB) {
    __shared__ int sd[256];
    __shared__ int excl[256];
    __shared__ int gbase[256];
    __shared__ int lcur[256];
    __shared__ int stage[TILE];
    __shared__ unsigned char bin8[TILE];
    int t = threadIdx.x;
    int ntiles = (E + TILE - 1) / TILE;
    for (int tile = blockIdx.x; tile < ntiles; tile += gridDim.x) {
        int base = tile * TILE;
        int cnt = min(TILE, E - base);
        sd[t] = 0;
        __syncthreads();
        for (int i = t; i < cnt; i += 256) {
            int s = ei[base + i];
            int d = ei[E + base + i];
            if ((unsigned)s < (unsigned)N && (unsigned)d < (unsigned)N)
                atomicAdd(&sd[d >> CB_BITS], 1);
        }
        __syncthreads();
        int v = sd[t];
        __syncthreads();
        for (int off = 1; off < 256; off <<= 1) {
            int add = (t >= off) ? sd[t - off] : 0;
            __syncthreads();
            sd[t] += add;
            __syncthreads();
        }
        int ex = sd[t] - v;
        excl[t] = ex;
        lcur[t] = ex;
        if (t < CB && v > 0) gbase[t] = atomicAdd(&gcursor[t * 16], v);
        int tot = sd[255];
        __syncthreads();
        for (int i = t; i < cnt; i += 256) {
            int s = ei[base + i];
            int d = ei[E + base + i];
            if ((unsigned)s < (unsigned)N && (unsigned)d < (unsigned)N) {
                int cb = d >> CB_BITS;
                int pos = atomicAdd(&lcur[cb], 1);
                stage[pos] = s | ((d & (CBS - 1)) << 17);
                bin8[pos] = (unsigned char)cb;
            }
        }
        __syncthreads();
        for (int i = t; i < tot; i += 256) {
            int b8 = bin8[i];
            pairs[gbase[b8] + (i - excl[b8])] = stage[i];
        }
        __syncthreads();
    }
}

// ---------------------------------------------------------------------------
// Per-coarse-bucket fine CSR (R7-proven).
// ---------------------------------------------------------------------------
__global__ __launch_bounds__(256)
void bucket_csr_kernel(const int* __restrict__ pairs, const int* __restrict__ bbase,
                       int* __restrict__ ebuf, int* __restrict__ rowptr, int N) {
    __shared__ int hist[CBS];
    __shared__ int cur[CBS];
    __shared__ int sd[256];
    __shared__ int carry_s;
    int b = blockIdx.x;
    int t = threadIdx.x;
    int pb = bbase[b], pe = bbase[b + 1];
    for (int i = t; i < CBS; i += 256) hist[i] = 0;
    if (t == 0) carry_s = 0;
    __syncthreads();
    for (int i = pb + t; i < pe; i += 256)
        atomicAdd(&hist[(pairs[i] >> 17) & (CBS - 1)], 1);
    __syncthreads();
    for (int start = 0; start < CBS; start += 256) {
        int v = hist[start + t];
        sd[t] = v; __syncthreads();
        for (int off = 1; off < 256; off <<= 1) {
            int add = (t >= off) ? sd[t - off] : 0;
            __syncthreads();
            sd[t] += add;
            __syncthreads();
        }
        int ex = sd[t] - v + carry_s;
        cur[start + t] = ex;
        int node = b * CBS + start + t;
        if (node < N) rowptr[node] = pb + ex;
        __syncthreads();
        if (t == 0) carry_s += sd[255];
        __syncthreads();
    }
    for (int i = pb + t; i < pe; i += 256) {
        int p = pairs[i];
        int pos = atomicAdd(&cur[(p >> 17) & (CBS - 1)], 1);
        ebuf[pb + pos] = p & 0x1FFFF;
    }
}

// ---------------------------------------------------------------------------
// Fold linear head:  (relu(z)@W2b + b2b)@LW + LB == relu(z)@Wf + bf
// ---------------------------------------------------------------------------
__global__ void fold_head_kernel(const float* __restrict__ W2b, const float* __restrict__ B2b,
                                 const float* __restrict__ LW, const float* __restrict__ LB,
                                 float* __restrict__ Wf, float* __restrict__ bf) {
    int t = blockIdx.x * blockDim.x + threadIdx.x;
    if (t < 640) {
        int k = t / 10, c = t % 10;
        float a = 0.f;
        for (int m = 0; m < H; ++m) a = fmaf(W2b[k * H + m], LW[m * 10 + c], a);
        Wf[t] = a;
    } else if (t < 650) {
        int c = t - 640;
        float a = LB[c];
        for (int m = 0; m < H; ++m) a = fmaf(B2b[m], LW[m * 10 + c], a);
        bf[c] = a;
    }
}

// ---------------------------------------------------------------------------
// Layer-1 gather: wave per node, 8-wide unguarded main loop + remainder.
// ---------------------------------------------------------------------------
__global__ __launch_bounds__(256)
void gather1_kernel(const float* __restrict__ x, const int* __restrict__ rowptr,
                    const int* __restrict__ ebuf, float* __restrict__ bufA, int N) {
    int wid = (int)(((long long)blockIdx.x * blockDim.x + threadIdx.x) >> 6);
    int lane = threadIdx.x & 63;
    if (wid >= N) return;
    int p0 = __builtin_amdgcn_readfirstlane(rowptr[wid]);
    int pe = __builtin_amdgcn_readfirstlane(rowptr[wid + 1]);
    float acc = x[((long long)wid << 6) + lane];
    int nfull = (pe - p0) & ~7;
    int p = p0;
    for (; p < p0 + nfull; p += 8) {
        float v0 = x[((long long)ebuf[p + 0] << 6) + lane];
        float v1 = x[((long long)ebuf[p + 1] << 6) + lane];
        float v2 = x[((long long)ebuf[p + 2] << 6) + lane];
        float v3 = x[((long long)ebuf[p + 3] << 6) + lane];
        float v4 = x[((long long)ebuf[p + 4] << 6) + lane];
        float v5 = x[((long long)ebuf[p + 5] << 6) + lane];
        float v6 = x[((long long)ebuf[p + 6] << 6) + lane];
        float v7 = x[((long long)ebuf[p + 7] << 6) + lane];
        acc += ((v0 + v1) + (v2 + v3)) + ((v4 + v5) + (v6 + v7));
    }
    for (; p < pe; ++p) acc += x[((long long)ebuf[p] << 6) + lane];
    bufA[((long long)wid << 6) + lane] = acc;
}

// ---------------------------------------------------------------------------
// Layer-2 gather with self row and full folded BN:
//   bufC = scale*(h1[self] + sum_j h1[j]) + (deg+1)*shift
// ---------------------------------------------------------------------------
__global__ __launch_bounds__(256)
void gather2_kernel(const float* __restrict__ h1p, const float* __restrict__ scale,
                    const float* __restrict__ shiftv, const int* __restrict__ rowptr,
                    const int* __restrict__ ebuf, float* __restrict__ bufC, int N) {
    int wid = (int)(((long long)blockIdx.x * blockDim.x + threadIdx.x) >> 6);
    int lane = threadIdx.x & 63;
    if (wid >= N) return;
    int p0 = __builtin_amdgcn_readfirstlane(rowptr[wid]);
    int pe = __builtin_amdgcn_readfirstlane(rowptr[wid + 1]);
    float acc = h1p[((long long)wid << 6) + lane];   // self
    int nfull = (pe - p0) & ~7;
    int p = p0;
    for (; p < p0 + nfull; p += 8) {
        float v0 = h1p[((long long)ebuf[p + 0] << 6) + lane];
        float v1 = h1p[((long long)ebuf[p + 1] << 6) + lane];
        float v2 = h1p[((long long)ebuf[p + 2] << 6) + lane];
        float v3 = h1p[((long long)ebuf[p + 3] << 6) + lane];
        float v4 = h1p[((long long)ebuf[p + 4] << 6) + lane];
        float v5 = h1p[((long long)ebuf[p + 5] << 6) + lane];
        float v6 = h1p[((long long)ebuf[p + 6] << 6) + lane];
        float v7 = h1p[((long long)ebuf[p + 7] << 6) + lane];
        acc += ((v0 + v1) + (v2 + v3)) + ((v4 + v5) + (v6 + v7));
    }
    for (; p < pe; ++p) acc += h1p[((long long)ebuf[p] << 6) + lane];
    float degp1 = (float)(pe - p0 + 1);
    bufC[((long long)wid << 6) + lane] = acc * scale[lane] + degp1 * shiftv[lane];
}

// ---------------------------------------------------------------------------
// MLP layer 1 + fused BN stats. Rolled k-loops; the intermediate u is stored
// in the thread's OWN LDS row (relu'd) so the second GEMM's dynamic-k read is
// an LDS read, not a dynamically-indexed register array (R9's scratch spill).
// Register arrays only ever indexed by statically-unrolled j.
// ---------------------------------------------------------------------------
__global__ __launch_bounds__(256)
void mlp1_kernel(const float* __restrict__ bufA, float* __restrict__ h1p,
                 const float* __restrict__ W1a, const float* __restrict__ B1a,
                 const float* __restrict__ W1b, const float* __restrict__ B1b,
                 float* __restrict__ stats, int N) {
    __shared__ float st[4][64 * PAD];     // 66.56 KB
    __shared__ float red[2][4][64];
    int t = threadIdx.x, wv = t >> 6, lane = t & 63;
    int node0 = (blockIdx.x * 4 + wv) * 64;
    float* S = st[wv];

#pragma unroll 8
    for (int r = 0; r < 64; ++r) {
        float v = bufA[((long long)(node0 + r) << 6) + lane];
        S[r * PAD + lane] = (node0 + r < N) ? v : 0.f;
    }
    bool valid = (node0 + lane < N);

    float u[H];
#pragma unroll
    for (int j = 0; j < H; ++j) u[j] = B1a[j];
#pragma unroll 1
    for (int k = 0; k < H; ++k) {
        float hk = S[lane * PAD + k];
#pragma unroll
        for (int j = 0; j < H; ++j) u[j] = fmaf(hk, W1a[k * H + j], u[j]);
    }
    // relu + stash u into own LDS row (input row is dead now)
#pragma unroll
    for (int j = 0; j < H; ++j) S[lane * PAD + j] = fmaxf(u[j], 0.f);

    float h1[H];
#pragma unroll
    for (int j = 0; j < H; ++j) h1[j] = B1b[j];
#pragma unroll 1
    for (int k = 0; k < H; ++k) {
        float uk = S[lane * PAD + k];
#pragma unroll
        for (int j = 0; j < H; ++j) h1[j] = fmaf(uk, W1b[k * H + j], h1[j]);
    }
#pragma unroll
    for (int j = 0; j < H; ++j) S[lane * PAD + j] = valid ? h1[j] : 0.f;

#pragma unroll 8
    for (int r = 0; r < 64; ++r) {
        if (node0 + r < N)
            h1p[((long long)(node0 + r) << 6) + lane] = S[r * PAD + lane];
    }
    float s = 0.f, s2 = 0.f;
#pragma unroll 8
    for (int r = 0; r < 64; ++r) {
        float v = S[r * PAD + lane];
        s += v;
        s2 = fmaf(v, v, s2);
    }
    red[0][wv][lane] = s;
    red[1][wv][lane] = s2;
    __syncthreads();
    if (wv == 0) {
        float ts  = (red[0][0][lane] + red[0][1][lane]) + (red[0][2][lane] + red[0][3][lane]);
        float ts2 = (red[1][0][lane] + red[1][1][lane]) + (red[1][2][lane] + red[1][3][lane]);
        unsafeAtomicAdd(&stats[lane], ts);
        unsafeAtomicAdd(&stats[H + lane], ts2);
    }
}

__global__ void bn_finalize_kernel(const float* __restrict__ stats,
                                   const float* __restrict__ gamma,
                                   const float* __restrict__ beta,
                                   float* __restrict__ scale, float* __restrict__ shiftv, float n) {
    int f = threadIdx.x;
    if (f >= H) return;
    float mean = stats[f] / n;
    float var = stats[H + f] / n - mean * mean;   // biased, matches jnp.var
    var = fmaxf(var, 0.f);
    float s = gamma[f] * rsqrtf(var + 1e-5f);
    scale[f] = s;
    shiftv[f] = beta[f] - mean * s;
}

// ---------------------------------------------------------------------------
// MLP layer 2 + folded head; same LDS round-trip for the relu intermediate.
// ---------------------------------------------------------------------------
__global__ __launch_bounds__(256)
void mlp2_kernel(const float* __restrict__ bufC,
                 const float* __restrict__ W2a, const float* __restrict__ B2a,
                 const float* __restrict__ Wf, const float* __restrict__ bf,
                 float* __restrict__ out, int N) {
    __shared__ float st[4][64 * PAD];     // 66.56 KB
    __shared__ float ost[4][64 * 11];     // 11.26 KB
    int t = threadIdx.x, wv = t >> 6, lane = t & 63;
    int node0 = (blockIdx.x * 4 + wv) * 64;
    float* S = st[wv];
    float* O = ost[wv];

#pragma unroll 8
    for (int r = 0; r < 64; ++r) {
        float v = bufC[((long long)(node0 + r) << 6) + lane];
        S[r * PAD + lane] = (node0 + r < N) ? v : 0.f;
    }
    float u[H];
#pragma unroll
    for (int j = 0; j < H; ++j) u[j] = B2a[j];
#pragma unroll 1
    for (int k = 0; k < H; ++k) {
        float hk = S[lane * PAD + k];
#pragma unroll
        for (int j = 0; j < H; ++j) u[j] = fmaf(hk, W2a[k * H + j], u[j]);
    }
#pragma unroll
    for (int j = 0; j < H; ++j) S[lane * PAD + j] = fmaxf(u[j], 0.f);

    float o[10];
#pragma unroll
    for (int c = 0; c < 10; ++c) o[c] = bf[c];
#pragma unroll 1
    for (int k = 0; k < H; ++k) {
        float uk = S[lane * PAD + k];
#pragma unroll
        for (int c = 0; c < 10; ++c) o[c] = fmaf(uk, Wf[k * 10 + c], o[c]);
    }
#pragma unroll
    for (int c = 0; c < 10; ++c) O[lane * 11 + c] = o[c];
    for (int i = lane; i < 640; i += 64) {
        int r = i / 10, c = i - r * 10;
        if (node0 + r < N)
            out[(long long)(node0 + r) * 10 + c] = O[r * 11 + c];
    }
}

extern "C" void kernel_launch(void* const* d_in, const int* in_sizes, int n_in,
                              void* d_out, int out_size, void* d_ws, size_t ws_size,
                              hipStream_t stream) {
    const float* x    = (const float*)d_in[0];
    const int*   ei   = (const int*)d_in[1];
    const float* w1a  = (const float*)d_in[2];
    const float* b1a  = (const float*)d_in[3];
    const float* w1b  = (const float*)d_in[4];
    const float* b1b  = (const float*)d_in[5];
    const float* bng  = (const float*)d_in[6];
    const float* bnb  = (const float*)d_in[7];
    const float* w2a  = (const float*)d_in[8];
    const float* b2a  = (const float*)d_in[9];
    const float* w2b  = (const float*)d_in[10];
    const float* b2b  = (const float*)d_in[11];
    const float* linw = (const float*)d_in[12];
    const float* linb = (const float*)d_in[13];

    int N = in_sizes[0] / H;       // 100000
    int E = in_sizes[1] / 2;       // 1600000
    int CB = (N + CBS - 1) / CBS;  // 196 coarse buckets

    // ---- workspace layout (pairs aliases bufC: lifetimes disjoint) ----
    float* ws     = (float*)d_ws;
    float* bufA   = ws;                          // N*H: agg1 -> h1p in place
    float* bufC   = ws + (size_t)N * H;          // N*H: full layer-2 input
    int*   pairs  = (int*)bufC;                  // E (dead before gather2 writes bufC)
    float* stats  = ws + 2 * (size_t)N * H;      // 128
    float* scale  = stats + 128;                 // 64
    float* shiftv = stats + 192;                 // 64
    float* Wf     = stats + 256;                 // 640
    float* bf     = Wf + 640;                    // 16
    int*   bcount = (int*)(bf + 16);             // 256
    int*   bbase  = bcount + 256;                // 257
    int*   cursor = bbase + 257;                 // 256*16
    int*   rowptr = cursor + 256 * 16;           // N+1
    int*   ebuf   = rowptr + (N + 1);            // E

    hipMemsetAsync(stats, 0, 128 * sizeof(float), stream);
    hipMemsetAsync(bcount, 0, 256 * sizeof(int), stream);

    int ntiles = (E + TILE - 1) / TILE;

    bhist_kernel<<<256, 256, 0, stream>>>(ei, bcount, E, N, CB);
    bscan_kernel<<<1, 256, 0, stream>>>(bcount, bbase, cursor, CB);
    rowptr_tail_kernel<<<1, 64, 0, stream>>>(bbase, rowptr, N, CB);
    part_staged_kernel<<<ntiles, 256, 0, stream>>>(ei, cursor, pairs, E, N, CB);
    bucket_csr_kernel<<<CB, 256, 0, stream>>>(pairs, bbase, ebuf, rowptr, N);
    fold_head_kernel<<<3, 256, 0, stream>>>(w2b, b2b, linw, linb, Wf, bf);

    int gblocks = (int)(((long long)N * 64 + 255) / 256);
    int mblocks = (N + 255) / 256;
    gather1_kernel<<<gblocks, 256, 0, stream>>>(x, rowptr, ebuf, bufA, N);
    mlp1_kernel<<<mblocks, 256, 0, stream>>>(bufA, bufA, w1a, b1a, w1b, b1b, stats, N);
    bn_finalize_kernel<<<1, 64, 0, stream>>>(stats, bng, bnb, scale, shiftv, (float)N);

    gather2_kernel<<<gblocks, 256, 0, stream>>>(bufA, scale, shiftv, rowptr, ebuf, bufC, N);
    mlp2_kernel<<<mblocks, 256, 0, stream>>>(bufC, w2a, b2a, Wf, bf, (float*)d_out, N);
}